// Round 3
// baseline (480.611 us; speedup 1.0000x reference)
//
#include <hip/hip_runtime.h>

constexpr int F  = 64;   // IN_FEATS == ATT_HEADS*H_FEATS
constexpr int HEADS = 4;

// ---------------------------------------------------------------------------
// Pass 1 (per node), fp32 arithmetic mirroring numpy BLAS (seq-k FMA from 0,
// bias added after):
//   tfeat = h@W_d + b_d        (stored; feeds literal sign fallback)
//   hp    = h@W_w + b_w
//   u = f64 tfeat.(Wf0+Wf2), v = f64 tfeat.(Wf1-Wf2)   (sign margin estimate)
//   a_src[q] = hp[q*16:].Wa[0:16], a_dst[q] = hp[q*16:].Wa[16:32]
// ---------------------------------------------------------------------------
__global__ __launch_bounds__(256) void node_kernel(
    const float* __restrict__ h,
    const float* __restrict__ W_w, const float* __restrict__ b_w,
    const float* __restrict__ W_a,
    const float* __restrict__ W_d, const float* __restrict__ b_d,
    const float* __restrict__ W_f,
    float* __restrict__ tfeat, float* __restrict__ hp,
    double* __restrict__ u_arr, double* __restrict__ v_arr,
    float* __restrict__ a_src, float* __restrict__ a_dst, int N)
{
    __shared__ float sWd[F * F];
    __shared__ float sWw[F * F];
    __shared__ double swfA[F], swfB[F];
    __shared__ float sbd[F], sbw[F], sWa[32];

    int tid = threadIdx.x;
    for (int i = tid; i < F * F; i += 256) { sWd[i] = W_d[i]; sWw[i] = W_w[i]; }
    if (tid < F) {
        swfA[tid] = (double)W_f[tid] + (double)W_f[2 * F + tid];
        swfB[tid] = (double)W_f[F + tid] - (double)W_f[2 * F + tid];
        sbd[tid] = b_d[tid];
        sbw[tid] = b_w[tid];
    }
    if (tid < 32) sWa[tid] = W_a[tid];
    __syncthreads();

    int n = blockIdx.x * 256 + tid;
    if (n >= N) return;

    float hv[F];
    const float4* h4 = reinterpret_cast<const float4*>(h + (size_t)n * F);
#pragma unroll
    for (int i = 0; i < F / 4; i++) {
        float4 x = h4[i];
        hv[4 * i + 0] = x.x; hv[4 * i + 1] = x.y;
        hv[4 * i + 2] = x.z; hv[4 * i + 3] = x.w;
    }

    double u = 0.0, v = 0.0;
    float as[HEADS] = {0.f, 0.f, 0.f, 0.f};
    float ad[HEADS] = {0.f, 0.f, 0.f, 0.f};

#pragma unroll 2
    for (int j = 0; j < F; j++) {
        float t = 0.f, p = 0.f;
#pragma unroll
        for (int k = 0; k < F; k++) {
            t = fmaf(hv[k], sWd[k * F + j], t);   // sequential-k, like sgemm
            p = fmaf(hv[k], sWw[k * F + j], p);
        }
        t = t + sbd[j];                            // bias after, like np broadcast add
        p = p + sbw[j];
        tfeat[(size_t)n * F + j] = t;
        hp[(size_t)n * F + j] = p;
        u = fma((double)t, swfA[j], u);
        v = fma((double)t, swfB[j], v);
        as[j >> 4] = fmaf(p, sWa[j & 15], as[j >> 4]);
        ad[j >> 4] = fmaf(p, sWa[16 + (j & 15)], ad[j >> 4]);
    }

    u_arr[n] = u;
    v_arr[n] = v;
#pragma unroll
    for (int q = 0; q < HEADS; q++) {
        a_src[n * HEADS + q] = as[q];
        a_dst[n * HEADS + q] = ad[q];
    }
}

// ---------------------------------------------------------------------------
// Pass 2 (per edge): 2-tier sign.
//   tier 1: |u[s]+v[d]+bf| >= 1e-4  ->  sign unambiguous at fp32 level.
//   tier 2 (rare, ~1e-4 of edges): literal fp32 192-term sequential FMA dot
//           in the reference's e_feat section order, matching its rounding.
// Then per head: ex = exp(leaky_relu(sign*a_src + a_dst + ba)); esum += ex.
// ---------------------------------------------------------------------------
__global__ __launch_bounds__(256) void edge_sign_softmax_kernel(
    const int* __restrict__ src_idx, const int* __restrict__ dst_idx,
    const double* __restrict__ u_arr, const double* __restrict__ v_arr,
    const float* __restrict__ tfeat,
    const float* __restrict__ a_src, const float* __restrict__ a_dst,
    const float* __restrict__ W_f, const float* __restrict__ b_f,
    const float* __restrict__ b_a,
    float* __restrict__ sgn_arr, float* __restrict__ esum, int E)
{
    __shared__ float sWf[3 * F];
    int tid = threadIdx.x;
    if (tid < 3 * F) sWf[tid] = W_f[tid];
    __syncthreads();

    int e = blockIdx.x * 256 + tid;
    if (e >= E) return;

    int s = src_idx[e], d = dst_idx[e];
    float bf = b_f[0], ba = b_a[0];

    double spre = u_arr[s] + v_arr[d] + (double)bf;
    float sgn;
    if (fabs(spre) >= 1e-4) {
        sgn = (spre > 0.0) ? 1.f : -1.f;
    } else {
        // literal reference-order fp32: sum_j s_j*Wf[j] ; + sum_j d_j*Wf[64+j] ;
        // + sum_j (s_j-d_j)*Wf[128+j] ; + b_f
        const float4* ts = reinterpret_cast<const float4*>(tfeat + (size_t)s * F);
        const float4* td = reinterpret_cast<const float4*>(tfeat + (size_t)d * F);
        float sv[F];
#pragma unroll
        for (int i = 0; i < 16; i++) {
            float4 a = ts[i];
            sv[4 * i + 0] = a.x; sv[4 * i + 1] = a.y;
            sv[4 * i + 2] = a.z; sv[4 * i + 3] = a.w;
        }
        float acc = 0.f;
#pragma unroll
        for (int j = 0; j < F; j++) acc = fmaf(sv[j], sWf[j], acc);
#pragma unroll
        for (int i = 0; i < 16; i++) {
            float4 a = td[i];
            acc = fmaf(a.x, sWf[F + 4 * i + 0], acc);
            acc = fmaf(a.y, sWf[F + 4 * i + 1], acc);
            acc = fmaf(a.z, sWf[F + 4 * i + 2], acc);
            acc = fmaf(a.w, sWf[F + 4 * i + 3], acc);
        }
#pragma unroll
        for (int i = 0; i < 16; i++) {
            float4 a = td[i];
            acc = fmaf(sv[4 * i + 0] - a.x, sWf[2 * F + 4 * i + 0], acc);
            acc = fmaf(sv[4 * i + 1] - a.y, sWf[2 * F + 4 * i + 1], acc);
            acc = fmaf(sv[4 * i + 2] - a.z, sWf[2 * F + 4 * i + 2], acc);
            acc = fmaf(sv[4 * i + 3] - a.w, sWf[2 * F + 4 * i + 3], acc);
        }
        float sp = acc + bf;
        sgn = (sp > 0.f) ? 1.f : (sp < 0.f ? -1.f : 0.f);
    }
    sgn_arr[e] = sgn;

    const float4 asv = *reinterpret_cast<const float4*>(a_src + (size_t)s * HEADS);
    const float4 adv = *reinterpret_cast<const float4*>(a_dst + (size_t)d * HEADS);
    float as_[4] = {asv.x, asv.y, asv.z, asv.w};
    float ad_[4] = {adv.x, adv.y, adv.z, adv.w};
#pragma unroll
    for (int q = 0; q < HEADS; q++) {
        float ap = fmaf(sgn, as_[q], ad_[q]) + ba;
        float al = ap > 0.f ? ap : 0.01f * ap;
        unsafeAtomicAdd(&esum[d * HEADS + q], expf(al));
    }
}

// ---------------------------------------------------------------------------
// Pass 3: one wave handles one edge at a time; lane c (0..63) = out component c.
// out[dst*64+c] += (ex/esum) * sign * hp[src*64+c]  -- coalesced atomics.
// ---------------------------------------------------------------------------
__global__ __launch_bounds__(256) void edge_scatter_kernel(
    const int* __restrict__ src_idx, const int* __restrict__ dst_idx,
    const float* __restrict__ sgn_arr,
    const float* __restrict__ a_src, const float* __restrict__ a_dst,
    const float* __restrict__ b_a,
    const float* __restrict__ hp, const float* __restrict__ esum,
    float* __restrict__ out, int E)
{
    float ba = b_a[0];
    int c = threadIdx.x & 63;
    int q = c >> 4;
    int slot = (blockIdx.x * 256 + threadIdx.x) >> 6;
    int nslots = (gridDim.x * 256) >> 6;
    for (int e = slot; e < E; e += nslots) {
        int s = src_idx[e], d = dst_idx[e];
        float sgn = sgn_arr[e];
        float ap = fmaf(sgn, a_src[s * HEADS + q], a_dst[d * HEADS + q]) + ba;
        float al = ap > 0.f ? ap : 0.01f * ap;
        float w = expf(al) / esum[d * HEADS + q];
        float val = w * sgn * hp[(size_t)s * F + c];
        unsafeAtomicAdd(&out[(size_t)d * F + c], val);
    }
}

// ---------------------------------------------------------------------------
extern "C" void kernel_launch(void* const* d_in, const int* in_sizes, int n_in,
                              void* d_out, int out_size, void* d_ws, size_t ws_size,
                              hipStream_t stream)
{
    const float* h       = (const float*)d_in[0];
    const int*   src_idx = (const int*)d_in[1];
    const int*   dst_idx = (const int*)d_in[2];
    const float* W_w     = (const float*)d_in[3];
    const float* b_w     = (const float*)d_in[4];
    const float* W_a     = (const float*)d_in[5];
    const float* b_a     = (const float*)d_in[6];
    const float* W_d     = (const float*)d_in[7];
    const float* b_d     = (const float*)d_in[8];
    const float* W_f     = (const float*)d_in[9];
    const float* b_f     = (const float*)d_in[10];

    int N = in_sizes[0] / F;
    int E = in_sizes[1];

    char* ws = (char*)d_ws;
    float*  tfeat = (float*)ws;   ws += (size_t)N * F * 4;      // 12.8MB
    float*  hp    = (float*)ws;   ws += (size_t)N * F * 4;      // 12.8MB
    double* u_arr = (double*)ws;  ws += (size_t)N * 8;          // 0.4MB
    double* v_arr = (double*)ws;  ws += (size_t)N * 8;          // 0.4MB
    float*  a_src = (float*)ws;   ws += (size_t)N * HEADS * 4;  // 0.8MB
    float*  a_dst = (float*)ws;   ws += (size_t)N * HEADS * 4;  // 0.8MB
    float*  esum  = (float*)ws;   ws += (size_t)N * HEADS * 4;  // 0.8MB
    float*  sgn   = (float*)ws;   ws += (size_t)E * 4;          // 4MB

    float* out = (float*)d_out;

    hipMemsetAsync(out, 0, (size_t)out_size * sizeof(float), stream);
    hipMemsetAsync(esum, 0, (size_t)N * HEADS * sizeof(float), stream);

    node_kernel<<<(N + 255) / 256, 256, 0, stream>>>(
        h, W_w, b_w, W_a, W_d, b_d, W_f, tfeat, hp, u_arr, v_arr, a_src, a_dst, N);

    edge_sign_softmax_kernel<<<(E + 255) / 256, 256, 0, stream>>>(
        src_idx, dst_idx, u_arr, v_arr, tfeat, a_src, a_dst, W_f, b_f, b_a,
        sgn, esum, E);

    edge_scatter_kernel<<<2048, 256, 0, stream>>>(
        src_idx, dst_idx, sgn, a_src, a_dst, b_a, hp, esum, out, E);
}

// Round 4
// 361.586 us; speedup vs baseline: 1.3292x; 1.3292x over previous
//
#include <hip/hip_runtime.h>

constexpr int F  = 64;   // IN_FEATS == ATT_HEADS*H_FEATS
constexpr int HEADS = 4;

// ---------------------------------------------------------------------------
// Pass 1 (per node), fp32 mirroring numpy BLAS (seq-k FMA from 0, bias after):
//   tfeat = h@W_d + b_d   (stored; feeds literal tier-2 sign fallback)
//   hp    = h@W_w + b_w
//   u = f64 tfeat.(Wf0+Wf2), v = f64 tfeat.(Wf1-Wf2)   (sign margin estimate)
//   a_src[q] = hp[q*16:].Wa[0:16], a_dst[q] = hp[q*16:].Wa[16:32]
// ---------------------------------------------------------------------------
__global__ __launch_bounds__(256) void node_kernel(
    const float* __restrict__ h,
    const float* __restrict__ W_w, const float* __restrict__ b_w,
    const float* __restrict__ W_a,
    const float* __restrict__ W_d, const float* __restrict__ b_d,
    const float* __restrict__ W_f,
    float* __restrict__ tfeat, float* __restrict__ hp,
    double* __restrict__ u_arr, double* __restrict__ v_arr,
    float* __restrict__ a_src, float* __restrict__ a_dst, int N)
{
    __shared__ float sWd[F * F];
    __shared__ float sWw[F * F];
    __shared__ double swfA[F], swfB[F];
    __shared__ float sbd[F], sbw[F], sWa[32];

    int tid = threadIdx.x;
    for (int i = tid; i < F * F; i += 256) { sWd[i] = W_d[i]; sWw[i] = W_w[i]; }
    if (tid < F) {
        swfA[tid] = (double)W_f[tid] + (double)W_f[2 * F + tid];
        swfB[tid] = (double)W_f[F + tid] - (double)W_f[2 * F + tid];
        sbd[tid] = b_d[tid];
        sbw[tid] = b_w[tid];
    }
    if (tid < 32) sWa[tid] = W_a[tid];
    __syncthreads();

    int n = blockIdx.x * 256 + tid;
    if (n >= N) return;

    float hv[F];
    const float4* h4 = reinterpret_cast<const float4*>(h + (size_t)n * F);
#pragma unroll
    for (int i = 0; i < F / 4; i++) {
        float4 x = h4[i];
        hv[4 * i + 0] = x.x; hv[4 * i + 1] = x.y;
        hv[4 * i + 2] = x.z; hv[4 * i + 3] = x.w;
    }

    double u = 0.0, v = 0.0;
    float as[HEADS] = {0.f, 0.f, 0.f, 0.f};
    float ad[HEADS] = {0.f, 0.f, 0.f, 0.f};

#pragma unroll 2
    for (int j = 0; j < F; j++) {
        float t = 0.f, p = 0.f;
#pragma unroll
        for (int k = 0; k < F; k++) {
            t = fmaf(hv[k], sWd[k * F + j], t);   // sequential-k, like sgemm
            p = fmaf(hv[k], sWw[k * F + j], p);
        }
        t = t + sbd[j];
        p = p + sbw[j];
        tfeat[(size_t)n * F + j] = t;
        hp[(size_t)n * F + j] = p;
        u = fma((double)t, swfA[j], u);
        v = fma((double)t, swfB[j], v);
        as[j >> 4] = fmaf(p, sWa[j & 15], as[j >> 4]);
        ad[j >> 4] = fmaf(p, sWa[16 + (j & 15)], ad[j >> 4]);
    }

    u_arr[n] = u;
    v_arr[n] = v;
#pragma unroll
    for (int q = 0; q < HEADS; q++) {
        a_src[n * HEADS + q] = as[q];
        a_dst[n * HEADS + q] = ad[q];
    }
}

// ---------------------------------------------------------------------------
// CSR step 1: histogram of dst
// ---------------------------------------------------------------------------
__global__ __launch_bounds__(256) void count_kernel(
    const int* __restrict__ dst_idx, unsigned* __restrict__ cnt, int E)
{
    int e = blockIdx.x * 256 + threadIdx.x;
    if (e < E) atomicAdd(&cnt[dst_idx[e]], 1u);
}

// ---------------------------------------------------------------------------
// CSR step 2: single-block exclusive scan of cnt -> rowptr (+ cursor copy woff)
// ---------------------------------------------------------------------------
__global__ __launch_bounds__(1024) void scan_kernel(
    const unsigned* __restrict__ cnt, unsigned* __restrict__ rowptr,
    unsigned* __restrict__ woff, int N)
{
    __shared__ unsigned part[1024];
    int t = threadIdx.x;
    int C = (N + 1023) / 1024;
    int lo = t * C;
    int hi = min(lo + C, N);
    unsigned s = 0;
    for (int i = lo; i < hi; i++) s += cnt[i];
    part[t] = s;
    __syncthreads();
    for (int off = 1; off < 1024; off <<= 1) {
        unsigned v = (t >= off) ? part[t - off] : 0u;
        __syncthreads();
        part[t] += v;
        __syncthreads();
    }
    unsigned run = (t == 0) ? 0u : part[t - 1];
    for (int i = lo; i < hi; i++) {
        rowptr[i] = run;
        woff[i] = run;
        run += cnt[i];
    }
    if (lo < N && hi == N) rowptr[N] = run;
}

// ---------------------------------------------------------------------------
// CSR step 3 + sign + per-head exp: scatter each edge into its dst bucket.
//   sign: tier1 = f64 collapsed margin; tier2 (|margin|<1e-4, ~1e-4 of edges)
//   = literal 192-term fp32 sequential FMA in the reference's section order.
//   Stores: src_packed (src | signcode<<30), ex4 = exp(leaky_relu(logits)).
// ---------------------------------------------------------------------------
__global__ __launch_bounds__(256) void edge_scatter_kernel(
    const int* __restrict__ src_idx, const int* __restrict__ dst_idx,
    const double* __restrict__ u_arr, const double* __restrict__ v_arr,
    const float* __restrict__ tfeat,
    const float* __restrict__ a_src, const float* __restrict__ a_dst,
    const float* __restrict__ W_f, const float* __restrict__ b_f,
    const float* __restrict__ b_a,
    unsigned* __restrict__ woff,
    unsigned* __restrict__ src_packed, float4* __restrict__ ex4_sorted, int E)
{
    __shared__ float sWf[3 * F];
    int tid = threadIdx.x;
    if (tid < 3 * F) sWf[tid] = W_f[tid];
    __syncthreads();

    int e = blockIdx.x * 256 + tid;
    if (e >= E) return;

    int s = src_idx[e], d = dst_idx[e];
    float bf = b_f[0], ba = b_a[0];

    double spre = u_arr[s] + v_arr[d] + (double)bf;
    float sgn;
    if (fabs(spre) >= 1e-4) {
        sgn = (spre > 0.0) ? 1.f : -1.f;
    } else {
        const float4* ts = reinterpret_cast<const float4*>(tfeat + (size_t)s * F);
        const float4* td = reinterpret_cast<const float4*>(tfeat + (size_t)d * F);
        float sv[F];
#pragma unroll
        for (int i = 0; i < 16; i++) {
            float4 a = ts[i];
            sv[4 * i + 0] = a.x; sv[4 * i + 1] = a.y;
            sv[4 * i + 2] = a.z; sv[4 * i + 3] = a.w;
        }
        float acc = 0.f;
#pragma unroll
        for (int j = 0; j < F; j++) acc = fmaf(sv[j], sWf[j], acc);
#pragma unroll
        for (int i = 0; i < 16; i++) {
            float4 a = td[i];
            acc = fmaf(a.x, sWf[F + 4 * i + 0], acc);
            acc = fmaf(a.y, sWf[F + 4 * i + 1], acc);
            acc = fmaf(a.z, sWf[F + 4 * i + 2], acc);
            acc = fmaf(a.w, sWf[F + 4 * i + 3], acc);
        }
#pragma unroll
        for (int i = 0; i < 16; i++) {
            float4 a = td[i];
            acc = fmaf(sv[4 * i + 0] - a.x, sWf[2 * F + 4 * i + 0], acc);
            acc = fmaf(sv[4 * i + 1] - a.y, sWf[2 * F + 4 * i + 1], acc);
            acc = fmaf(sv[4 * i + 2] - a.z, sWf[2 * F + 4 * i + 2], acc);
            acc = fmaf(sv[4 * i + 3] - a.w, sWf[2 * F + 4 * i + 3], acc);
        }
        float sp = acc + bf;
        sgn = (sp > 0.f) ? 1.f : (sp < 0.f ? -1.f : 0.f);
    }

    const float4 asv = *reinterpret_cast<const float4*>(a_src + (size_t)s * HEADS);
    const float4 adv = *reinterpret_cast<const float4*>(a_dst + (size_t)d * HEADS);
    float ex[4];
    {
        float as_[4] = {asv.x, asv.y, asv.z, asv.w};
        float ad_[4] = {adv.x, adv.y, adv.z, adv.w};
#pragma unroll
        for (int q = 0; q < HEADS; q++) {
            float ap = fmaf(sgn, as_[q], ad_[q]) + ba;
            float al = ap > 0.f ? ap : 0.01f * ap;
            ex[q] = expf(al);
        }
    }

    unsigned code = (sgn > 0.f) ? 0u : (sgn < 0.f ? 1u : 2u);
    unsigned pos = atomicAdd(&woff[d], 1u);
    src_packed[pos] = (unsigned)s | (code << 30);
    ex4_sorted[pos] = make_float4(ex[0], ex[1], ex[2], ex[3]);
}

// ---------------------------------------------------------------------------
// Pass 4: one wave per dst. Phase A: lanes sum ex4 edge-parallel, shfl-reduce
// -> esum (no atomics). Phase B: sequential edge loop, uniform loads; lane c
// accumulates out component c from coalesced hp[src] row. One store per dst.
// ---------------------------------------------------------------------------
__global__ __launch_bounds__(256) void dst_gather_kernel(
    const unsigned* __restrict__ rowptr,
    const unsigned* __restrict__ src_packed,
    const float4* __restrict__ ex4_sorted,
    const float* __restrict__ hp,
    float* __restrict__ out, int N)
{
    int lane = threadIdx.x & 63;
    int q = lane >> 4;
    int wid = (blockIdx.x * 256 + threadIdx.x) >> 6;
    int nw = (gridDim.x * 256) >> 6;

    for (int d = wid; d < N; d += nw) {
        unsigned start = rowptr[d], end = rowptr[d + 1];

        // Phase A: esum over edges (4 heads), edge-parallel then butterfly
        float4 p = make_float4(0.f, 0.f, 0.f, 0.f);
        for (unsigned i = start + lane; i < end; i += 64) {
            float4 x = ex4_sorted[i];
            p.x += x.x; p.y += x.y; p.z += x.z; p.w += x.w;
        }
#pragma unroll
        for (int off = 32; off >= 1; off >>= 1) {
            p.x += __shfl_xor(p.x, off);
            p.y += __shfl_xor(p.y, off);
            p.z += __shfl_xor(p.z, off);
            p.w += __shfl_xor(p.w, off);
        }
        // per-lane reciprocal of this lane's head
        float esq = (q == 0) ? p.x : (q == 1) ? p.y : (q == 2) ? p.z : p.w;
        float rinv = 1.0f / esq;   // unused if no edges

        // Phase B: weighted signed accumulation of hp rows
        float acc = 0.f;
        for (unsigned i = start; i < end; i++) {
            unsigned sp = src_packed[i];
            float4 x = ex4_sorted[i];
            unsigned s = sp & 0x3FFFFFFFu;
            unsigned code = sp >> 30;
            float sgnf = (code == 0u) ? 1.f : (code == 1u ? -1.f : 0.f);
            float exq = (q == 0) ? x.x : (q == 1) ? x.y : (q == 2) ? x.z : x.w;
            float w = exq * rinv * sgnf;
            acc = fmaf(w, hp[((size_t)s << 6) | (unsigned)lane], acc);
        }
        out[((size_t)d << 6) | (unsigned)lane] = acc;
    }
}

// ---------------------------------------------------------------------------
extern "C" void kernel_launch(void* const* d_in, const int* in_sizes, int n_in,
                              void* d_out, int out_size, void* d_ws, size_t ws_size,
                              hipStream_t stream)
{
    const float* h       = (const float*)d_in[0];
    const int*   src_idx = (const int*)d_in[1];
    const int*   dst_idx = (const int*)d_in[2];
    const float* W_w     = (const float*)d_in[3];
    const float* b_w     = (const float*)d_in[4];
    const float* W_a     = (const float*)d_in[5];
    const float* b_a     = (const float*)d_in[6];
    const float* W_d     = (const float*)d_in[7];
    const float* b_d     = (const float*)d_in[8];
    const float* W_f     = (const float*)d_in[9];
    const float* b_f     = (const float*)d_in[10];

    int N = in_sizes[0] / F;
    int E = in_sizes[1];

    char* ws = (char*)d_ws;
    float*    tfeat = (float*)ws;      ws += (size_t)N * F * 4;        // 12.8MB
    float*    hp    = (float*)ws;      ws += (size_t)N * F * 4;        // 12.8MB
    double*   u_arr = (double*)ws;     ws += (size_t)N * 8;            // 0.4MB
    double*   v_arr = (double*)ws;     ws += (size_t)N * 8;            // 0.4MB
    float*    a_src = (float*)ws;      ws += (size_t)N * HEADS * 4;    // 0.8MB
    float*    a_dst = (float*)ws;      ws += (size_t)N * HEADS * 4;    // 0.8MB
    unsigned* cnt   = (unsigned*)ws;   ws += (size_t)N * 4;            // 0.2MB
    unsigned* rowptr= (unsigned*)ws;   ws += ((size_t)N + 4) * 4;      // 0.2MB
    unsigned* woff  = (unsigned*)ws;   ws += (size_t)N * 4;            // 0.2MB
    unsigned* src_p = (unsigned*)ws;   ws += (size_t)E * 4;            // 4MB
    float4*   ex4   = (float4*)ws;     ws += (size_t)E * 16;           // 16MB

    float* out = (float*)d_out;

    hipMemsetAsync(cnt, 0, (size_t)N * sizeof(unsigned), stream);

    node_kernel<<<(N + 255) / 256, 256, 0, stream>>>(
        h, W_w, b_w, W_a, W_d, b_d, W_f, tfeat, hp, u_arr, v_arr, a_src, a_dst, N);

    count_kernel<<<(E + 255) / 256, 256, 0, stream>>>(dst_idx, cnt, E);

    scan_kernel<<<1, 1024, 0, stream>>>(cnt, rowptr, woff, N);

    edge_scatter_kernel<<<(E + 255) / 256, 256, 0, stream>>>(
        src_idx, dst_idx, u_arr, v_arr, tfeat, a_src, a_dst, W_f, b_f, b_a,
        woff, src_p, ex4, E);

    dst_gather_kernel<<<4096, 256, 0, stream>>>(
        rowptr, src_p, ex4, hp, out, N);
}

// Round 5
// 225.763 us; speedup vs baseline: 2.1288x; 1.6016x over previous
//
#include <hip/hip_runtime.h>

constexpr int F  = 64;   // IN_FEATS == ATT_HEADS*H_FEATS
constexpr int HEADS = 4;

// ---------------------------------------------------------------------------
// Pass 1 (per node), fp32 mirroring numpy BLAS (seq-k FMA from 0, bias after):
//   tfeat = h@W_d + b_d   (stored; feeds literal tier-2 sign fallback)
//   hp    = h@W_w + b_w
//   u = f64 tfeat.(Wf0+Wf2), v = f64 tfeat.(Wf1-Wf2)   (sign margin estimate)
//   a_src[q] = hp[q*16:].Wa[0:16], a_dst[q] = hp[q*16:].Wa[16:32]
// ---------------------------------------------------------------------------
__global__ __launch_bounds__(256) void node_kernel(
    const float* __restrict__ h,
    const float* __restrict__ W_w, const float* __restrict__ b_w,
    const float* __restrict__ W_a,
    const float* __restrict__ W_d, const float* __restrict__ b_d,
    const float* __restrict__ W_f,
    float* __restrict__ tfeat, float* __restrict__ hp,
    double* __restrict__ u_arr, double* __restrict__ v_arr,
    float* __restrict__ a_src, float* __restrict__ a_dst, int N)
{
    __shared__ float sWd[F * F];
    __shared__ float sWw[F * F];
    __shared__ double swfA[F], swfB[F];
    __shared__ float sbd[F], sbw[F], sWa[32];

    int tid = threadIdx.x;
    for (int i = tid; i < F * F; i += 256) { sWd[i] = W_d[i]; sWw[i] = W_w[i]; }
    if (tid < F) {
        swfA[tid] = (double)W_f[tid] + (double)W_f[2 * F + tid];
        swfB[tid] = (double)W_f[F + tid] - (double)W_f[2 * F + tid];
        sbd[tid] = b_d[tid];
        sbw[tid] = b_w[tid];
    }
    if (tid < 32) sWa[tid] = W_a[tid];
    __syncthreads();

    int n = blockIdx.x * 256 + tid;
    if (n >= N) return;

    float hv[F];
    const float4* h4 = reinterpret_cast<const float4*>(h + (size_t)n * F);
#pragma unroll
    for (int i = 0; i < F / 4; i++) {
        float4 x = h4[i];
        hv[4 * i + 0] = x.x; hv[4 * i + 1] = x.y;
        hv[4 * i + 2] = x.z; hv[4 * i + 3] = x.w;
    }

    double u = 0.0, v = 0.0;
    float as[HEADS] = {0.f, 0.f, 0.f, 0.f};
    float ad[HEADS] = {0.f, 0.f, 0.f, 0.f};

#pragma unroll 2
    for (int j = 0; j < F; j++) {
        float t = 0.f, p = 0.f;
#pragma unroll
        for (int k = 0; k < F; k++) {
            t = fmaf(hv[k], sWd[k * F + j], t);   // sequential-k, like sgemm
            p = fmaf(hv[k], sWw[k * F + j], p);
        }
        t = t + sbd[j];
        p = p + sbw[j];
        tfeat[(size_t)n * F + j] = t;
        hp[(size_t)n * F + j] = p;
        u = fma((double)t, swfA[j], u);
        v = fma((double)t, swfB[j], v);
        as[j >> 4] = fmaf(p, sWa[j & 15], as[j >> 4]);
        ad[j >> 4] = fmaf(p, sWa[16 + (j & 15)], ad[j >> 4]);
    }

    u_arr[n] = u;
    v_arr[n] = v;
#pragma unroll
    for (int q = 0; q < HEADS; q++) {
        a_src[n * HEADS + q] = as[q];
        a_dst[n * HEADS + q] = ad[q];
    }
}

// ---------------------------------------------------------------------------
// CSR step 1: histogram of dst
// ---------------------------------------------------------------------------
__global__ __launch_bounds__(256) void count_kernel(
    const int* __restrict__ dst_idx, unsigned* __restrict__ cnt, int E)
{
    int e = blockIdx.x * 256 + threadIdx.x;
    if (e < E) atomicAdd(&cnt[dst_idx[e]], 1u);
}

// ---------------------------------------------------------------------------
// CSR step 2a: per-256-chunk exclusive scan (shfl wave scan + wave combine);
// local exclusive -> rowptr, chunk total -> bsum
// ---------------------------------------------------------------------------
__global__ __launch_bounds__(256) void scan1_kernel(
    const unsigned* __restrict__ cnt, unsigned* __restrict__ rowptr,
    unsigned* __restrict__ bsum, int N)
{
    int t = threadIdx.x;
    int i = blockIdx.x * 256 + t;
    unsigned v = (i < N) ? cnt[i] : 0u;

    unsigned x = v;
#pragma unroll
    for (int off = 1; off < 64; off <<= 1) {
        unsigned y = __shfl_up(x, off);
        if ((t & 63) >= off) x += y;
    }
    __shared__ unsigned wsum[4];
    if ((t & 63) == 63) wsum[t >> 6] = x;
    __syncthreads();
    unsigned pre = 0;
#pragma unroll
    for (int w = 0; w < 3; w++) if (w < (t >> 6)) pre += wsum[w];
    unsigned incl = x + pre;
    if (i < N) rowptr[i] = incl - v;     // local exclusive
    if (t == 255) bsum[blockIdx.x] = incl;
}

// ---------------------------------------------------------------------------
// CSR step 2b: single block scans the <=256 block totals (exclusive, in place)
// ---------------------------------------------------------------------------
__global__ __launch_bounds__(256) void scan2_kernel(unsigned* __restrict__ bsum, int nb)
{
    int t = threadIdx.x;
    unsigned v = (t < nb) ? bsum[t] : 0u;
    __syncthreads();
    unsigned x = v;
#pragma unroll
    for (int off = 1; off < 64; off <<= 1) {
        unsigned y = __shfl_up(x, off);
        if ((t & 63) >= off) x += y;
    }
    __shared__ unsigned wsum[4];
    if ((t & 63) == 63) wsum[t >> 6] = x;
    __syncthreads();
    unsigned pre = 0;
#pragma unroll
    for (int w = 0; w < 3; w++) if (w < (t >> 6)) pre += wsum[w];
    if (t < nb) bsum[t] = x + pre - v;   // exclusive
}

// ---------------------------------------------------------------------------
// CSR step 2c: add chunk offsets, mirror to woff, set rowptr[N]=E
// ---------------------------------------------------------------------------
__global__ __launch_bounds__(256) void scan3_kernel(
    unsigned* __restrict__ rowptr, const unsigned* __restrict__ bsum,
    unsigned* __restrict__ woff, int N, int E)
{
    int i = blockIdx.x * 256 + threadIdx.x;
    if (i < N) {
        unsigned r = rowptr[i] + bsum[blockIdx.x];
        rowptr[i] = r;
        woff[i] = r;
    }
    if (i == 0) rowptr[N] = (unsigned)E;
}

// ---------------------------------------------------------------------------
// CSR step 3 + sign + per-head exp: scatter each edge into its dst bucket.
//   sign: tier1 = f64 collapsed margin; tier2 (|margin|<1e-4, ~1e-4 of edges)
//   = literal 192-term fp32 sequential FMA in the reference's section order.
//   Stores: src_packed (src | signcode<<30), ex4 = exp(leaky_relu(logits)).
// ---------------------------------------------------------------------------
__global__ __launch_bounds__(256) void edge_scatter_kernel(
    const int* __restrict__ src_idx, const int* __restrict__ dst_idx,
    const double* __restrict__ u_arr, const double* __restrict__ v_arr,
    const float* __restrict__ tfeat,
    const float* __restrict__ a_src, const float* __restrict__ a_dst,
    const float* __restrict__ W_f, const float* __restrict__ b_f,
    const float* __restrict__ b_a,
    unsigned* __restrict__ woff,
    unsigned* __restrict__ src_packed, float4* __restrict__ ex4_sorted, int E)
{
    __shared__ float sWf[3 * F];
    int tid = threadIdx.x;
    if (tid < 3 * F) sWf[tid] = W_f[tid];
    __syncthreads();

    int e = blockIdx.x * 256 + tid;
    if (e >= E) return;

    int s = src_idx[e], d = dst_idx[e];
    float bf = b_f[0], ba = b_a[0];

    double spre = u_arr[s] + v_arr[d] + (double)bf;
    float sgn;
    if (fabs(spre) >= 1e-4) {
        sgn = (spre > 0.0) ? 1.f : -1.f;
    } else {
        const float4* ts = reinterpret_cast<const float4*>(tfeat + (size_t)s * F);
        const float4* td = reinterpret_cast<const float4*>(tfeat + (size_t)d * F);
        float sv[F];
#pragma unroll
        for (int i = 0; i < 16; i++) {
            float4 a = ts[i];
            sv[4 * i + 0] = a.x; sv[4 * i + 1] = a.y;
            sv[4 * i + 2] = a.z; sv[4 * i + 3] = a.w;
        }
        float acc = 0.f;
#pragma unroll
        for (int j = 0; j < F; j++) acc = fmaf(sv[j], sWf[j], acc);
#pragma unroll
        for (int i = 0; i < 16; i++) {
            float4 a = td[i];
            acc = fmaf(a.x, sWf[F + 4 * i + 0], acc);
            acc = fmaf(a.y, sWf[F + 4 * i + 1], acc);
            acc = fmaf(a.z, sWf[F + 4 * i + 2], acc);
            acc = fmaf(a.w, sWf[F + 4 * i + 3], acc);
        }
#pragma unroll
        for (int i = 0; i < 16; i++) {
            float4 a = td[i];
            acc = fmaf(sv[4 * i + 0] - a.x, sWf[2 * F + 4 * i + 0], acc);
            acc = fmaf(sv[4 * i + 1] - a.y, sWf[2 * F + 4 * i + 1], acc);
            acc = fmaf(sv[4 * i + 2] - a.z, sWf[2 * F + 4 * i + 2], acc);
            acc = fmaf(sv[4 * i + 3] - a.w, sWf[2 * F + 4 * i + 3], acc);
        }
        float sp = acc + bf;
        sgn = (sp > 0.f) ? 1.f : (sp < 0.f ? -1.f : 0.f);
    }

    const float4 asv = *reinterpret_cast<const float4*>(a_src + (size_t)s * HEADS);
    const float4 adv = *reinterpret_cast<const float4*>(a_dst + (size_t)d * HEADS);
    float ex[4];
    {
        float as_[4] = {asv.x, asv.y, asv.z, asv.w};
        float ad_[4] = {adv.x, adv.y, adv.z, adv.w};
#pragma unroll
        for (int q = 0; q < HEADS; q++) {
            float ap = fmaf(sgn, as_[q], ad_[q]) + ba;
            float al = ap > 0.f ? ap : 0.01f * ap;
            ex[q] = expf(al);
        }
    }

    unsigned code = (sgn > 0.f) ? 0u : (sgn < 0.f ? 1u : 2u);
    unsigned pos = atomicAdd(&woff[d], 1u);
    src_packed[pos] = (unsigned)s | (code << 30);
    ex4_sorted[pos] = make_float4(ex[0], ex[1], ex[2], ex[3]);
}

// ---------------------------------------------------------------------------
// Pass 4: one wave per dst. Phase A: lanes sum ex4 edge-parallel, shfl-reduce
// -> esum (no atomics). Phase B: sequential edge loop (2-way ILP), uniform
// loads; lane c accumulates out component c from coalesced hp[src] row.
// ---------------------------------------------------------------------------
__global__ __launch_bounds__(256) void dst_gather_kernel(
    const unsigned* __restrict__ rowptr,
    const unsigned* __restrict__ src_packed,
    const float4* __restrict__ ex4_sorted,
    const float* __restrict__ hp,
    float* __restrict__ out, int N)
{
    int lane = threadIdx.x & 63;
    int q = lane >> 4;
    int wid = (blockIdx.x * 256 + threadIdx.x) >> 6;
    int nw = (gridDim.x * 256) >> 6;

    for (int d = wid; d < N; d += nw) {
        unsigned start = rowptr[d], end = rowptr[d + 1];

        // Phase A: esum over edges (4 heads), edge-parallel then butterfly
        float4 p = make_float4(0.f, 0.f, 0.f, 0.f);
        for (unsigned i = start + lane; i < end; i += 64) {
            float4 x = ex4_sorted[i];
            p.x += x.x; p.y += x.y; p.z += x.z; p.w += x.w;
        }
#pragma unroll
        for (int off = 32; off >= 1; off >>= 1) {
            p.x += __shfl_xor(p.x, off);
            p.y += __shfl_xor(p.y, off);
            p.z += __shfl_xor(p.z, off);
            p.w += __shfl_xor(p.w, off);
        }
        float esq = (q == 0) ? p.x : (q == 1) ? p.y : (q == 2) ? p.z : p.w;
        float rinv = 1.0f / esq;   // unused if no edges

        // Phase B: weighted signed accumulation of hp rows, 2-way ILP
        float acc0 = 0.f, acc1 = 0.f;
        unsigned i = start;
        for (; i + 1 < end; i += 2) {
            unsigned sp0 = src_packed[i], sp1 = src_packed[i + 1];
            float4 x0 = ex4_sorted[i];
            float4 x1 = ex4_sorted[i + 1];
            unsigned s0 = sp0 & 0x3FFFFFFFu, s1 = sp1 & 0x3FFFFFFFu;
            unsigned c0 = sp0 >> 30, c1 = sp1 >> 30;
            float g0 = (c0 == 0u) ? 1.f : (c0 == 1u ? -1.f : 0.f);
            float g1 = (c1 == 0u) ? 1.f : (c1 == 1u ? -1.f : 0.f);
            float e0 = (q == 0) ? x0.x : (q == 1) ? x0.y : (q == 2) ? x0.z : x0.w;
            float e1 = (q == 0) ? x1.x : (q == 1) ? x1.y : (q == 2) ? x1.z : x1.w;
            acc0 = fmaf(e0 * rinv * g0, hp[((size_t)s0 << 6) | (unsigned)lane], acc0);
            acc1 = fmaf(e1 * rinv * g1, hp[((size_t)s1 << 6) | (unsigned)lane], acc1);
        }
        if (i < end) {
            unsigned sp = src_packed[i];
            float4 x = ex4_sorted[i];
            unsigned s = sp & 0x3FFFFFFFu;
            unsigned c = sp >> 30;
            float g = (c == 0u) ? 1.f : (c == 1u ? -1.f : 0.f);
            float eq = (q == 0) ? x.x : (q == 1) ? x.y : (q == 2) ? x.z : x.w;
            acc0 = fmaf(eq * rinv * g, hp[((size_t)s << 6) | (unsigned)lane], acc0);
        }
        out[((size_t)d << 6) | (unsigned)lane] = acc0 + acc1;
    }
}

// ---------------------------------------------------------------------------
extern "C" void kernel_launch(void* const* d_in, const int* in_sizes, int n_in,
                              void* d_out, int out_size, void* d_ws, size_t ws_size,
                              hipStream_t stream)
{
    const float* h       = (const float*)d_in[0];
    const int*   src_idx = (const int*)d_in[1];
    const int*   dst_idx = (const int*)d_in[2];
    const float* W_w     = (const float*)d_in[3];
    const float* b_w     = (const float*)d_in[4];
    const float* W_a     = (const float*)d_in[5];
    const float* b_a     = (const float*)d_in[6];
    const float* W_d     = (const float*)d_in[7];
    const float* b_d     = (const float*)d_in[8];
    const float* W_f     = (const float*)d_in[9];
    const float* b_f     = (const float*)d_in[10];

    int N = in_sizes[0] / F;
    int E = in_sizes[1];
    int nb = (N + 255) / 256;

    char* ws = (char*)d_ws;
    float*    tfeat = (float*)ws;      ws += (size_t)N * F * 4;        // 12.8MB
    float*    hp    = (float*)ws;      ws += (size_t)N * F * 4;        // 12.8MB
    double*   u_arr = (double*)ws;     ws += (size_t)N * 8;            // 0.4MB
    double*   v_arr = (double*)ws;     ws += (size_t)N * 8;            // 0.4MB
    float*    a_src = (float*)ws;      ws += (size_t)N * HEADS * 4;    // 0.8MB
    float*    a_dst = (float*)ws;      ws += (size_t)N * HEADS * 4;    // 0.8MB
    unsigned* cnt   = (unsigned*)ws;   ws += (size_t)N * 4;            // 0.2MB
    unsigned* rowptr= (unsigned*)ws;   ws += ((size_t)N + 4) * 4;      // 0.2MB
    unsigned* woff  = (unsigned*)ws;   ws += (size_t)N * 4;            // 0.2MB
    unsigned* bsum  = (unsigned*)ws;   ws += 1024;                     // 1KB
    unsigned* src_p = (unsigned*)ws;   ws += (size_t)E * 4;            // 4MB
    float4*   ex4   = (float4*)ws;     ws += (size_t)E * 16;           // 16MB

    float* out = (float*)d_out;

    hipMemsetAsync(cnt, 0, (size_t)N * sizeof(unsigned), stream);

    node_kernel<<<(N + 255) / 256, 256, 0, stream>>>(
        h, W_w, b_w, W_a, W_d, b_d, W_f, tfeat, hp, u_arr, v_arr, a_src, a_dst, N);

    count_kernel<<<(E + 255) / 256, 256, 0, stream>>>(dst_idx, cnt, E);

    scan1_kernel<<<nb, 256, 0, stream>>>(cnt, rowptr, bsum, N);
    scan2_kernel<<<1, 256, 0, stream>>>(bsum, nb);
    scan3_kernel<<<nb, 256, 0, stream>>>(rowptr, bsum, woff, N, E);

    edge_scatter_kernel<<<(E + 255) / 256, 256, 0, stream>>>(
        src_idx, dst_idx, u_arr, v_arr, tfeat, a_src, a_dst, W_f, b_f, b_a,
        woff, src_p, ex4, E);

    dst_gather_kernel<<<4096, 256, 0, stream>>>(
        rowptr, src_p, ex4, hp, out, N);
}

// Round 6
// 215.066 us; speedup vs baseline: 2.2347x; 1.0497x over previous
//
#include <hip/hip_runtime.h>

constexpr int F  = 64;   // IN_FEATS == ATT_HEADS*H_FEATS
constexpr int HEADS = 4;

// ---------------------------------------------------------------------------
// Pass 1 (per node), fp32 mirroring numpy BLAS (seq-k FMA from 0, bias after).
// Split across 2*nb blocks: blocks [0,nb) do the W_d path (tfeat,u,v),
// blocks [nb,2nb) do the W_w path (hp, a_src, a_dst). Both co-resident.
// W stored TRANSPOSED in LDS so inner k-loop reads are ds_read_b128.
// ---------------------------------------------------------------------------
__global__ __launch_bounds__(256) void node_kernel(
    const float* __restrict__ h,
    const float* __restrict__ W_w, const float* __restrict__ b_w,
    const float* __restrict__ W_a,
    const float* __restrict__ W_d, const float* __restrict__ b_d,
    const float* __restrict__ W_f,
    float* __restrict__ tfeat, float* __restrict__ hp,
    double* __restrict__ u_arr, double* __restrict__ v_arr,
    float* __restrict__ a_src, float* __restrict__ a_dst, int N, int nb)
{
    __shared__ float sWT[F * F];     // [j][k] transposed
    __shared__ float sb[F];
    __shared__ double swfA[F], swfB[F];
    __shared__ float sWa[32];

    int tid = threadIdx.x;
    bool isW = blockIdx.x >= nb;     // W_w path?
    const float* Wsrc = isW ? W_w : W_d;
    for (int i = tid; i < F * F; i += 256) {
        int k = i >> 6, j = i & 63;
        sWT[j * F + k] = Wsrc[i];
    }
    if (tid < F) sb[tid] = isW ? b_w[tid] : b_d[tid];
    if (!isW && tid < F) {
        swfA[tid] = (double)W_f[tid] + (double)W_f[2 * F + tid];
        swfB[tid] = (double)W_f[F + tid] - (double)W_f[2 * F + tid];
    }
    if (isW && tid < 32) sWa[tid] = W_a[tid];
    __syncthreads();

    int blk = isW ? (blockIdx.x - nb) : blockIdx.x;
    int n = blk * 256 + tid;
    if (n >= N) return;

    float4 hv[16];
    const float4* h4 = reinterpret_cast<const float4*>(h + (size_t)n * F);
#pragma unroll
    for (int i = 0; i < 16; i++) hv[i] = h4[i];

    if (!isW) {
        // ---- W_d path: tfeat row + u,v (f64, j-sequential) ----
        double u = 0.0, v = 0.0;
        float4 tq;
        float4* trow = reinterpret_cast<float4*>(tfeat + (size_t)n * F);
#pragma unroll 4
        for (int j = 0; j < F; j++) {
            const float4* row = reinterpret_cast<const float4*>(&sWT[j * F]);
            float t = 0.f;
#pragma unroll
            for (int kk = 0; kk < 16; kk++) {
                float4 w = row[kk];
                float4 x = hv[kk];
                t = fmaf(x.x, w.x, t);
                t = fmaf(x.y, w.y, t);
                t = fmaf(x.z, w.z, t);
                t = fmaf(x.w, w.w, t);
            }
            t = t + sb[j];
            u = fma((double)t, swfA[j], u);
            v = fma((double)t, swfB[j], v);
            if ((j & 3) == 0) tq.x = t;
            else if ((j & 3) == 1) tq.y = t;
            else if ((j & 3) == 2) tq.z = t;
            else { tq.w = t; trow[j >> 2] = tq; }
        }
        u_arr[n] = u;
        v_arr[n] = v;
    } else {
        // ---- W_w path: hp row + a_src,a_dst per head ----
        float4* prow = reinterpret_cast<float4*>(hp + (size_t)n * F);
#pragma unroll
        for (int qh = 0; qh < 4; qh++) {
            float asq = 0.f, adq = 0.f;
            float4 pq;
#pragma unroll 4
            for (int jj = 0; jj < 16; jj++) {
                int j = qh * 16 + jj;
                const float4* row = reinterpret_cast<const float4*>(&sWT[j * F]);
                float p = 0.f;
#pragma unroll
                for (int kk = 0; kk < 16; kk++) {
                    float4 w = row[kk];
                    float4 x = hv[kk];
                    p = fmaf(x.x, w.x, p);
                    p = fmaf(x.y, w.y, p);
                    p = fmaf(x.z, w.z, p);
                    p = fmaf(x.w, w.w, p);
                }
                p = p + sb[j];
                asq = fmaf(p, sWa[jj], asq);
                adq = fmaf(p, sWa[16 + jj], adq);
                if ((jj & 3) == 0) pq.x = p;
                else if ((jj & 3) == 1) pq.y = p;
                else if ((jj & 3) == 2) pq.z = p;
                else { pq.w = p; prow[j >> 2] = pq; }
            }
            a_src[n * HEADS + qh] = asq;
            a_dst[n * HEADS + qh] = adq;
        }
    }
}

// ---------------------------------------------------------------------------
// CSR step 1: histogram of dst
// ---------------------------------------------------------------------------
__global__ __launch_bounds__(256) void count_kernel(
    const int* __restrict__ dst_idx, unsigned* __restrict__ cnt, int E)
{
    int e = blockIdx.x * 256 + threadIdx.x;
    if (e < E) atomicAdd(&cnt[dst_idx[e]], 1u);
}

// ---------------------------------------------------------------------------
// CSR step 2a/2b/2c: hierarchical exclusive scan
// ---------------------------------------------------------------------------
__global__ __launch_bounds__(256) void scan1_kernel(
    const unsigned* __restrict__ cnt, unsigned* __restrict__ rowptr,
    unsigned* __restrict__ bsum, int N)
{
    int t = threadIdx.x;
    int i = blockIdx.x * 256 + t;
    unsigned v = (i < N) ? cnt[i] : 0u;
    unsigned x = v;
#pragma unroll
    for (int off = 1; off < 64; off <<= 1) {
        unsigned y = __shfl_up(x, off);
        if ((t & 63) >= off) x += y;
    }
    __shared__ unsigned wsum[4];
    if ((t & 63) == 63) wsum[t >> 6] = x;
    __syncthreads();
    unsigned pre = 0;
#pragma unroll
    for (int w = 0; w < 3; w++) if (w < (t >> 6)) pre += wsum[w];
    unsigned incl = x + pre;
    if (i < N) rowptr[i] = incl - v;
    if (t == 255) bsum[blockIdx.x] = incl;
}

__global__ __launch_bounds__(256) void scan2_kernel(unsigned* __restrict__ bsum, int nb)
{
    int t = threadIdx.x;
    unsigned v = (t < nb) ? bsum[t] : 0u;
    unsigned x = v;
#pragma unroll
    for (int off = 1; off < 64; off <<= 1) {
        unsigned y = __shfl_up(x, off);
        if ((t & 63) >= off) x += y;
    }
    __shared__ unsigned wsum[4];
    if ((t & 63) == 63) wsum[t >> 6] = x;
    __syncthreads();
    unsigned pre = 0;
#pragma unroll
    for (int w = 0; w < 3; w++) if (w < (t >> 6)) pre += wsum[w];
    if (t < nb) bsum[t] = x + pre - v;
}

__global__ __launch_bounds__(256) void scan3_kernel(
    unsigned* __restrict__ rowptr, const unsigned* __restrict__ bsum,
    unsigned* __restrict__ woff, int N, int E)
{
    int i = blockIdx.x * 256 + threadIdx.x;
    if (i < N) {
        unsigned r = rowptr[i] + bsum[blockIdx.x];
        rowptr[i] = r;
        woff[i] = r;
    }
    if (i == 0) rowptr[N] = (unsigned)E;
}

// ---------------------------------------------------------------------------
// Tier-2 sign fallback: literal fp32 192-term sequential FMA in the
// reference's e_feat section order (rare: |f64 margin| < 1e-4).
// ---------------------------------------------------------------------------
__device__ __noinline__ float tier2_sign(
    const float* __restrict__ tfeat, const float* __restrict__ sWf,
    int s, int d, float bf)
{
    const float4* ts = reinterpret_cast<const float4*>(tfeat + (size_t)s * F);
    const float4* td = reinterpret_cast<const float4*>(tfeat + (size_t)d * F);
    float sv[F];
#pragma unroll
    for (int i = 0; i < 16; i++) {
        float4 a = ts[i];
        sv[4 * i + 0] = a.x; sv[4 * i + 1] = a.y;
        sv[4 * i + 2] = a.z; sv[4 * i + 3] = a.w;
    }
    float acc = 0.f;
#pragma unroll
    for (int j = 0; j < F; j++) acc = fmaf(sv[j], sWf[j], acc);
#pragma unroll
    for (int i = 0; i < 16; i++) {
        float4 a = td[i];
        acc = fmaf(a.x, sWf[F + 4 * i + 0], acc);
        acc = fmaf(a.y, sWf[F + 4 * i + 1], acc);
        acc = fmaf(a.z, sWf[F + 4 * i + 2], acc);
        acc = fmaf(a.w, sWf[F + 4 * i + 3], acc);
    }
#pragma unroll
    for (int i = 0; i < 16; i++) {
        float4 a = td[i];
        acc = fmaf(sv[4 * i + 0] - a.x, sWf[2 * F + 4 * i + 0], acc);
        acc = fmaf(sv[4 * i + 1] - a.y, sWf[2 * F + 4 * i + 1], acc);
        acc = fmaf(sv[4 * i + 2] - a.z, sWf[2 * F + 4 * i + 2], acc);
        acc = fmaf(sv[4 * i + 3] - a.w, sWf[2 * F + 4 * i + 3], acc);
    }
    float sp = acc + bf;
    return (sp > 0.f) ? 1.f : (sp < 0.f ? -1.f : 0.f);
}

// ---------------------------------------------------------------------------
// CSR step 3 + sign + exp: 2 edges per thread (independent chains), atomics
// issued early (depend only on dst). Stores src_packed + ex4 into CSR slots.
// ---------------------------------------------------------------------------
__global__ __launch_bounds__(256) void edge_scatter_kernel(
    const int* __restrict__ src_idx, const int* __restrict__ dst_idx,
    const double* __restrict__ u_arr, const double* __restrict__ v_arr,
    const float* __restrict__ tfeat,
    const float* __restrict__ a_src, const float* __restrict__ a_dst,
    const float* __restrict__ W_f, const float* __restrict__ b_f,
    const float* __restrict__ b_a,
    unsigned* __restrict__ woff,
    unsigned* __restrict__ src_packed, float4* __restrict__ ex4_sorted, int E)
{
    __shared__ float sWf[3 * F];
    int tid = threadIdx.x;
    if (tid < 3 * F) sWf[tid] = W_f[tid];
    __syncthreads();

    float bf = b_f[0], ba = b_a[0];
    int e0 = blockIdx.x * 512 + tid;
    int e1 = e0 + 256;
    bool ok0 = e0 < E, ok1 = e1 < E;

    int s0 = 0, d0 = 0, s1 = 0, d1 = 0;
    if (ok0) { s0 = src_idx[e0]; d0 = dst_idx[e0]; }
    if (ok1) { s1 = src_idx[e1]; d1 = dst_idx[e1]; }

    // atomics early: only depend on dst
    unsigned p0 = ok0 ? atomicAdd(&woff[d0], 1u) : 0u;
    unsigned p1 = ok1 ? atomicAdd(&woff[d1], 1u) : 0u;

    double m0 = ok0 ? (u_arr[s0] + v_arr[d0] + (double)bf) : 1.0;
    double m1 = ok1 ? (u_arr[s1] + v_arr[d1] + (double)bf) : 1.0;

    float4 A0 = {0,0,0,0}, D0 = {0,0,0,0}, A1 = {0,0,0,0}, D1 = {0,0,0,0};
    if (ok0) {
        A0 = *reinterpret_cast<const float4*>(a_src + (size_t)s0 * HEADS);
        D0 = *reinterpret_cast<const float4*>(a_dst + (size_t)d0 * HEADS);
    }
    if (ok1) {
        A1 = *reinterpret_cast<const float4*>(a_src + (size_t)s1 * HEADS);
        D1 = *reinterpret_cast<const float4*>(a_dst + (size_t)d1 * HEADS);
    }

    float sg0 = (fabs(m0) >= 1e-4) ? ((m0 > 0.0) ? 1.f : -1.f)
                                   : (ok0 ? tier2_sign(tfeat, sWf, s0, d0, bf) : 0.f);
    float sg1 = (fabs(m1) >= 1e-4) ? ((m1 > 0.0) ? 1.f : -1.f)
                                   : (ok1 ? tier2_sign(tfeat, sWf, s1, d1, bf) : 0.f);

    if (ok0) {
        float ex[4];
        float as_[4] = {A0.x, A0.y, A0.z, A0.w};
        float ad_[4] = {D0.x, D0.y, D0.z, D0.w};
#pragma unroll
        for (int q = 0; q < HEADS; q++) {
            float ap = fmaf(sg0, as_[q], ad_[q]) + ba;
            float al = ap > 0.f ? ap : 0.01f * ap;
            ex[q] = expf(al);
        }
        unsigned code = (sg0 > 0.f) ? 0u : (sg0 < 0.f ? 1u : 2u);
        src_packed[p0] = (unsigned)s0 | (code << 30);
        ex4_sorted[p0] = make_float4(ex[0], ex[1], ex[2], ex[3]);
    }
    if (ok1) {
        float ex[4];
        float as_[4] = {A1.x, A1.y, A1.z, A1.w};
        float ad_[4] = {D1.x, D1.y, D1.z, D1.w};
#pragma unroll
        for (int q = 0; q < HEADS; q++) {
            float ap = fmaf(sg1, as_[q], ad_[q]) + ba;
            float al = ap > 0.f ? ap : 0.01f * ap;
            ex[q] = expf(al);
        }
        unsigned code = (sg1 > 0.f) ? 0u : (sg1 < 0.f ? 1u : 2u);
        src_packed[p1] = (unsigned)s1 | (code << 30);
        ex4_sorted[p1] = make_float4(ex[0], ex[1], ex[2], ex[3]);
    }
}

// ---------------------------------------------------------------------------
// Pass 4: one wave per dst. Phase A: edge-parallel esum + butterfly reduce.
// Phase B: 4-way ILP edge loop; lane c accumulates component c; normalize
// once at the end (acc * rinv). One coalesced 256B store per dst.
// ---------------------------------------------------------------------------
__global__ __launch_bounds__(256) void dst_gather_kernel(
    const unsigned* __restrict__ rowptr,
    const unsigned* __restrict__ src_packed,
    const float4* __restrict__ ex4_sorted,
    const float* __restrict__ hp,
    float* __restrict__ out, int N)
{
    int lane = threadIdx.x & 63;
    int q = lane >> 4;
    int d = (blockIdx.x * 256 + threadIdx.x) >> 6;
    if (d >= N) return;

    unsigned start = rowptr[d], end = rowptr[d + 1];

    // Phase A
    float4 p = make_float4(0.f, 0.f, 0.f, 0.f);
    for (unsigned i = start + lane; i < end; i += 64) {
        float4 x = ex4_sorted[i];
        p.x += x.x; p.y += x.y; p.z += x.z; p.w += x.w;
    }
#pragma unroll
    for (int off = 32; off >= 1; off >>= 1) {
        p.x += __shfl_xor(p.x, off);
        p.y += __shfl_xor(p.y, off);
        p.z += __shfl_xor(p.z, off);
        p.w += __shfl_xor(p.w, off);
    }
    float esq = (q == 0) ? p.x : (q == 1) ? p.y : (q == 2) ? p.z : p.w;
    float rinv = (end > start) ? (1.0f / esq) : 0.f;

    // Phase B: 4-way ILP
    float a0 = 0.f, a1 = 0.f, a2 = 0.f, a3 = 0.f;
    unsigned i = start;
    for (; i + 4 <= end; i += 4) {
        unsigned sp0 = src_packed[i + 0], sp1 = src_packed[i + 1];
        unsigned sp2 = src_packed[i + 2], sp3 = src_packed[i + 3];
        float4 x0 = ex4_sorted[i + 0], x1 = ex4_sorted[i + 1];
        float4 x2 = ex4_sorted[i + 2], x3 = ex4_sorted[i + 3];
        unsigned c0 = sp0 >> 30, c1 = sp1 >> 30, c2 = sp2 >> 30, c3 = sp3 >> 30;
        float g0 = (c0 == 0u) ? 1.f : (c0 == 1u ? -1.f : 0.f);
        float g1 = (c1 == 0u) ? 1.f : (c1 == 1u ? -1.f : 0.f);
        float g2 = (c2 == 0u) ? 1.f : (c2 == 1u ? -1.f : 0.f);
        float g3 = (c3 == 0u) ? 1.f : (c3 == 1u ? -1.f : 0.f);
        float e0 = (q == 0) ? x0.x : (q == 1) ? x0.y : (q == 2) ? x0.z : x0.w;
        float e1 = (q == 0) ? x1.x : (q == 1) ? x1.y : (q == 2) ? x1.z : x1.w;
        float e2 = (q == 0) ? x2.x : (q == 1) ? x2.y : (q == 2) ? x2.z : x2.w;
        float e3 = (q == 0) ? x3.x : (q == 1) ? x3.y : (q == 2) ? x3.z : x3.w;
        size_t s0 = (size_t)(sp0 & 0x3FFFFFFFu), s1 = (size_t)(sp1 & 0x3FFFFFFFu);
        size_t s2 = (size_t)(sp2 & 0x3FFFFFFFu), s3 = (size_t)(sp3 & 0x3FFFFFFFu);
        a0 = fmaf(e0 * g0, hp[(s0 << 6) | (unsigned)lane], a0);
        a1 = fmaf(e1 * g1, hp[(s1 << 6) | (unsigned)lane], a1);
        a2 = fmaf(e2 * g2, hp[(s2 << 6) | (unsigned)lane], a2);
        a3 = fmaf(e3 * g3, hp[(s3 << 6) | (unsigned)lane], a3);
    }
    for (; i < end; i++) {
        unsigned sp = src_packed[i];
        float4 x = ex4_sorted[i];
        unsigned c = sp >> 30;
        float g = (c == 0u) ? 1.f : (c == 1u ? -1.f : 0.f);
        float eq = (q == 0) ? x.x : (q == 1) ? x.y : (q == 2) ? x.z : x.w;
        size_t s = (size_t)(sp & 0x3FFFFFFFu);
        a0 = fmaf(eq * g, hp[(s << 6) | (unsigned)lane], a0);
    }
    out[((size_t)d << 6) | (unsigned)lane] = ((a0 + a1) + (a2 + a3)) * rinv;
}

// ---------------------------------------------------------------------------
extern "C" void kernel_launch(void* const* d_in, const int* in_sizes, int n_in,
                              void* d_out, int out_size, void* d_ws, size_t ws_size,
                              hipStream_t stream)
{
    const float* h       = (const float*)d_in[0];
    const int*   src_idx = (const int*)d_in[1];
    const int*   dst_idx = (const int*)d_in[2];
    const float* W_w     = (const float*)d_in[3];
    const float* b_w     = (const float*)d_in[4];
    const float* W_a     = (const float*)d_in[5];
    const float* b_a     = (const float*)d_in[6];
    const float* W_d     = (const float*)d_in[7];
    const float* b_d     = (const float*)d_in[8];
    const float* W_f     = (const float*)d_in[9];
    const float* b_f     = (const float*)d_in[10];

    int N = in_sizes[0] / F;
    int E = in_sizes[1];
    int nb = (N + 255) / 256;

    char* ws = (char*)d_ws;
    float*    tfeat = (float*)ws;      ws += (size_t)N * F * 4;        // 12.8MB
    float*    hp    = (float*)ws;      ws += (size_t)N * F * 4;        // 12.8MB
    double*   u_arr = (double*)ws;     ws += (size_t)N * 8;            // 0.4MB
    double*   v_arr = (double*)ws;     ws += (size_t)N * 8;            // 0.4MB
    float*    a_src = (float*)ws;      ws += (size_t)N * HEADS * 4;    // 0.8MB
    float*    a_dst = (float*)ws;      ws += (size_t)N * HEADS * 4;    // 0.8MB
    unsigned* cnt   = (unsigned*)ws;   ws += (size_t)N * 4;            // 0.2MB
    unsigned* rowptr= (unsigned*)ws;   ws += ((size_t)N + 4) * 4;      // 0.2MB
    unsigned* woff  = (unsigned*)ws;   ws += (size_t)N * 4;            // 0.2MB
    unsigned* bsum  = (unsigned*)ws;   ws += 1024;                     // 1KB
    unsigned* src_p = (unsigned*)ws;   ws += (size_t)E * 4;            // 4MB
    float4*   ex4   = (float4*)ws;     ws += (size_t)E * 16;           // 16MB

    float* out = (float*)d_out;

    hipMemsetAsync(cnt, 0, (size_t)N * sizeof(unsigned), stream);

    node_kernel<<<2 * nb, 256, 0, stream>>>(
        h, W_w, b_w, W_a, W_d, b_d, W_f, tfeat, hp, u_arr, v_arr, a_src, a_dst,
        N, nb);

    count_kernel<<<(E + 255) / 256, 256, 0, stream>>>(dst_idx, cnt, E);

    scan1_kernel<<<nb, 256, 0, stream>>>(cnt, rowptr, bsum, N);
    scan2_kernel<<<1, 256, 0, stream>>>(bsum, nb);
    scan3_kernel<<<nb, 256, 0, stream>>>(rowptr, bsum, woff, N, E);

    edge_scatter_kernel<<<(E + 511) / 512, 256, 0, stream>>>(
        src_idx, dst_idx, u_arr, v_arr, tfeat, a_src, a_dst, W_f, b_f, b_a,
        woff, src_p, ex4, E);

    dst_gather_kernel<<<(N * 64 + 255) / 256, 256, 0, stream>>>(
        rowptr, src_p, ex4, hp, out, N);
}

// Round 7
// 181.957 us; speedup vs baseline: 2.6413x; 1.1820x over previous
//
#include <hip/hip_runtime.h>
#include <hip/hip_fp16.h>

constexpr int F  = 64;   // IN_FEATS == ATT_HEADS*H_FEATS
constexpr int HEADS = 4;

// ---------------------------------------------------------------------------
// Pass 1 (per node), fp32 mirroring numpy BLAS (seq-k FMA from 0, bias after).
// Blocks [0,nb): W_d path (tfeat fp32, u/v f64). Blocks [nb,2nb): W_w path
// (hp as fp16, a_src/a_dst fp32). W transposed in LDS -> ds_read_b128.
// ---------------------------------------------------------------------------
__global__ __launch_bounds__(256) void node_kernel(
    const float* __restrict__ h,
    const float* __restrict__ W_w, const float* __restrict__ b_w,
    const float* __restrict__ W_a,
    const float* __restrict__ W_d, const float* __restrict__ b_d,
    const float* __restrict__ W_f,
    float* __restrict__ tfeat, __half* __restrict__ hp,
    double* __restrict__ u_arr, double* __restrict__ v_arr,
    float* __restrict__ a_src, float* __restrict__ a_dst, int N, int nb)
{
    __shared__ float sWT[F * F];     // [j][k] transposed
    __shared__ float sb[F];
    __shared__ double swfA[F], swfB[F];
    __shared__ float sWa[32];

    int tid = threadIdx.x;
    bool isW = blockIdx.x >= nb;     // W_w path?
    const float* Wsrc = isW ? W_w : W_d;
    for (int i = tid; i < F * F; i += 256) {
        int k = i >> 6, j = i & 63;
        sWT[j * F + k] = Wsrc[i];
    }
    if (tid < F) sb[tid] = isW ? b_w[tid] : b_d[tid];
    if (!isW && tid < F) {
        swfA[tid] = (double)W_f[tid] + (double)W_f[2 * F + tid];
        swfB[tid] = (double)W_f[F + tid] - (double)W_f[2 * F + tid];
    }
    if (isW && tid < 32) sWa[tid] = W_a[tid];
    __syncthreads();

    int blk = isW ? (blockIdx.x - nb) : blockIdx.x;
    int n = blk * 256 + tid;
    if (n >= N) return;

    float4 hv[16];
    const float4* h4 = reinterpret_cast<const float4*>(h + (size_t)n * F);
#pragma unroll
    for (int i = 0; i < 16; i++) hv[i] = h4[i];

    if (!isW) {
        // ---- W_d path: tfeat row + u,v (f64, j-sequential) ----
        double u = 0.0, v = 0.0;
        float4 tq;
        float4* trow = reinterpret_cast<float4*>(tfeat + (size_t)n * F);
#pragma unroll 4
        for (int j = 0; j < F; j++) {
            const float4* row = reinterpret_cast<const float4*>(&sWT[j * F]);
            float t = 0.f;
#pragma unroll
            for (int kk = 0; kk < 16; kk++) {
                float4 w = row[kk];
                float4 x = hv[kk];
                t = fmaf(x.x, w.x, t);
                t = fmaf(x.y, w.y, t);
                t = fmaf(x.z, w.z, t);
                t = fmaf(x.w, w.w, t);
            }
            t = t + sb[j];
            u = fma((double)t, swfA[j], u);
            v = fma((double)t, swfB[j], v);
            if ((j & 3) == 0) tq.x = t;
            else if ((j & 3) == 1) tq.y = t;
            else if ((j & 3) == 2) tq.z = t;
            else { tq.w = t; trow[j >> 2] = tq; }
        }
        u_arr[n] = u;
        v_arr[n] = v;
    } else {
        // ---- W_w path: hp row (fp16) + a_src,a_dst per head ----
        __half2* prow = reinterpret_cast<__half2*>(hp + (size_t)n * F);
#pragma unroll
        for (int qh = 0; qh < 4; qh++) {
            float asq = 0.f, adq = 0.f;
            float pprev = 0.f;
#pragma unroll 4
            for (int jj = 0; jj < 16; jj++) {
                int j = qh * 16 + jj;
                const float4* row = reinterpret_cast<const float4*>(&sWT[j * F]);
                float p = 0.f;
#pragma unroll
                for (int kk = 0; kk < 16; kk++) {
                    float4 w = row[kk];
                    float4 x = hv[kk];
                    p = fmaf(x.x, w.x, p);
                    p = fmaf(x.y, w.y, p);
                    p = fmaf(x.z, w.z, p);
                    p = fmaf(x.w, w.w, p);
                }
                p = p + sb[j];
                asq = fmaf(p, sWa[jj], asq);
                adq = fmaf(p, sWa[16 + jj], adq);
                if ((jj & 1) == 0) pprev = p;
                else prow[j >> 1] = __floats2half2_rn(pprev, p);
            }
            a_src[n * HEADS + qh] = asq;
            a_dst[n * HEADS + qh] = adq;
        }
    }
}

// ---------------------------------------------------------------------------
// Tier-2 sign fallback: literal fp32 192-term sequential FMA in the
// reference's e_feat section order (rare: |f64 margin| < 1e-4).
// ---------------------------------------------------------------------------
__device__ __noinline__ float tier2_sign(
    const float* __restrict__ tfeat, const float* __restrict__ sWf,
    int s, int d, float bf)
{
    const float4* ts = reinterpret_cast<const float4*>(tfeat + (size_t)s * F);
    const float4* td = reinterpret_cast<const float4*>(tfeat + (size_t)d * F);
    float sv[F];
#pragma unroll
    for (int i = 0; i < 16; i++) {
        float4 a = ts[i];
        sv[4 * i + 0] = a.x; sv[4 * i + 1] = a.y;
        sv[4 * i + 2] = a.z; sv[4 * i + 3] = a.w;
    }
    float acc = 0.f;
#pragma unroll
    for (int j = 0; j < F; j++) acc = fmaf(sv[j], sWf[j], acc);
#pragma unroll
    for (int i = 0; i < 16; i++) {
        float4 a = td[i];
        acc = fmaf(a.x, sWf[F + 4 * i + 0], acc);
        acc = fmaf(a.y, sWf[F + 4 * i + 1], acc);
        acc = fmaf(a.z, sWf[F + 4 * i + 2], acc);
        acc = fmaf(a.w, sWf[F + 4 * i + 3], acc);
    }
#pragma unroll
    for (int i = 0; i < 16; i++) {
        float4 a = td[i];
        acc = fmaf(sv[4 * i + 0] - a.x, sWf[2 * F + 4 * i + 0], acc);
        acc = fmaf(sv[4 * i + 1] - a.y, sWf[2 * F + 4 * i + 1], acc);
        acc = fmaf(sv[4 * i + 2] - a.z, sWf[2 * F + 4 * i + 2], acc);
        acc = fmaf(sv[4 * i + 3] - a.w, sWf[2 * F + 4 * i + 3], acc);
    }
    float sp = acc + bf;
    return (sp > 0.f) ? 1.f : (sp < 0.f ? -1.f : 0.f);
}

// ---------------------------------------------------------------------------
// CSR step 1 + sign: pos[e] = atomicAdd(cnt[dst],1); sign per edge (f64 tier1,
// literal tier2). pc[e] = pos | code<<30   (coalesced 4B store by e).
// ---------------------------------------------------------------------------
__global__ __launch_bounds__(256) void count_sign_kernel(
    const int* __restrict__ src_idx, const int* __restrict__ dst_idx,
    const double* __restrict__ u_arr, const double* __restrict__ v_arr,
    const float* __restrict__ tfeat, const float* __restrict__ W_f,
    const float* __restrict__ b_f,
    unsigned* __restrict__ cnt, unsigned* __restrict__ pc, int E)
{
    __shared__ float sWf[3 * F];
    int tid = threadIdx.x;
    if (tid < 3 * F) sWf[tid] = W_f[tid];
    __syncthreads();

    int e = blockIdx.x * 256 + tid;
    if (e >= E) return;

    int s = src_idx[e], d = dst_idx[e];
    float bf = b_f[0];

    unsigned pos = atomicAdd(&cnt[d], 1u);      // independent of sign chain

    double m = u_arr[s] + v_arr[d] + (double)bf;
    float sgn = (fabs(m) >= 1e-4) ? ((m > 0.0) ? 1.f : -1.f)
                                  : tier2_sign(tfeat, sWf, s, d, bf);
    unsigned code = (sgn > 0.f) ? 0u : (sgn < 0.f ? 1u : 2u);
    pc[e] = pos | (code << 30);
}

// ---------------------------------------------------------------------------
// CSR step 2a/2b/2c: hierarchical exclusive scan -> rowptr
// ---------------------------------------------------------------------------
__global__ __launch_bounds__(256) void scan1_kernel(
    const unsigned* __restrict__ cnt, unsigned* __restrict__ rowptr,
    unsigned* __restrict__ bsum, int N)
{
    int t = threadIdx.x;
    int i = blockIdx.x * 256 + t;
    unsigned v = (i < N) ? cnt[i] : 0u;
    unsigned x = v;
#pragma unroll
    for (int off = 1; off < 64; off <<= 1) {
        unsigned y = __shfl_up(x, off);
        if ((t & 63) >= off) x += y;
    }
    __shared__ unsigned wsum[4];
    if ((t & 63) == 63) wsum[t >> 6] = x;
    __syncthreads();
    unsigned pre = 0;
#pragma unroll
    for (int w = 0; w < 3; w++) if (w < (t >> 6)) pre += wsum[w];
    unsigned incl = x + pre;
    if (i < N) rowptr[i] = incl - v;
    if (t == 255) bsum[blockIdx.x] = incl;
}

__global__ __launch_bounds__(256) void scan2_kernel(unsigned* __restrict__ bsum, int nb)
{
    int t = threadIdx.x;
    unsigned v = (t < nb) ? bsum[t] : 0u;
    unsigned x = v;
#pragma unroll
    for (int off = 1; off < 64; off <<= 1) {
        unsigned y = __shfl_up(x, off);
        if ((t & 63) >= off) x += y;
    }
    __shared__ unsigned wsum[4];
    if ((t & 63) == 63) wsum[t >> 6] = x;
    __syncthreads();
    unsigned pre = 0;
#pragma unroll
    for (int w = 0; w < 3; w++) if (w < (t >> 6)) pre += wsum[w];
    if (t < nb) bsum[t] = x + pre - v;
}

__global__ __launch_bounds__(256) void scan3_kernel(
    unsigned* __restrict__ rowptr, const unsigned* __restrict__ bsum, int N, int E)
{
    int i = blockIdx.x * 256 + threadIdx.x;
    if (i < N) rowptr[i] += bsum[blockIdx.x];
    if (i == 0) rowptr[N] = (unsigned)E;
}

// ---------------------------------------------------------------------------
// CSR step 3: pure placement. 4B scattered store per edge, no atomics.
// ---------------------------------------------------------------------------
__global__ __launch_bounds__(256) void place_kernel(
    const int* __restrict__ src_idx, const int* __restrict__ dst_idx,
    const unsigned* __restrict__ pc, const unsigned* __restrict__ rowptr,
    unsigned* __restrict__ src_packed, int E)
{
    int e = blockIdx.x * 256 + threadIdx.x;
    if (e >= E) return;
    unsigned p = pc[e];
    unsigned pos = p & 0x3FFFFFFFu;
    unsigned code = p & 0xC0000000u;
    int d = dst_idx[e];
    src_packed[rowptr[d] + pos] = (unsigned)src_idx[e] | code;
}

// ---------------------------------------------------------------------------
// Pass 4: one wave per dst. ex recomputed from L2-resident a_src/a_dst.
// Phase A: edge-parallel esum (per-lane float4 over heads) + butterfly.
// Phase B: 4-way ILP; lane c accumulates component c from fp16 hp row (128B).
// ---------------------------------------------------------------------------
__global__ __launch_bounds__(256) void dst_gather_kernel(
    const unsigned* __restrict__ rowptr,
    const unsigned* __restrict__ src_packed,
    const float* __restrict__ a_src, const float* __restrict__ a_dst,
    const float* __restrict__ b_a,
    const __half* __restrict__ hp,
    float* __restrict__ out, int N)
{
    int lane = threadIdx.x & 63;
    int q = lane >> 4;
    int d = (blockIdx.x * 256 + threadIdx.x) >> 6;
    if (d >= N) return;

    unsigned start = rowptr[d], end = rowptr[d + 1];
    float ba = b_a[0];
    float4 ad4 = *reinterpret_cast<const float4*>(a_dst + (size_t)d * HEADS);
    float adq = (q == 0) ? ad4.x : (q == 1) ? ad4.y : (q == 2) ? ad4.z : ad4.w;

    // Phase A: per-lane edges, all 4 heads each
    float4 p = make_float4(0.f, 0.f, 0.f, 0.f);
    for (unsigned i = start + lane; i < end; i += 64) {
        unsigned sp = src_packed[i];
        unsigned s = sp & 0x3FFFFFFFu;
        unsigned c = sp >> 30;
        float sgn = (c == 0u) ? 1.f : (c == 1u ? -1.f : 0.f);
        float4 as4 = *reinterpret_cast<const float4*>(a_src + (size_t)s * HEADS);
        float ap0 = fmaf(sgn, as4.x, ad4.x) + ba;
        float ap1 = fmaf(sgn, as4.y, ad4.y) + ba;
        float ap2 = fmaf(sgn, as4.z, ad4.z) + ba;
        float ap3 = fmaf(sgn, as4.w, ad4.w) + ba;
        p.x += expf(ap0 > 0.f ? ap0 : 0.01f * ap0);
        p.y += expf(ap1 > 0.f ? ap1 : 0.01f * ap1);
        p.z += expf(ap2 > 0.f ? ap2 : 0.01f * ap2);
        p.w += expf(ap3 > 0.f ? ap3 : 0.01f * ap3);
    }
#pragma unroll
    for (int off = 32; off >= 1; off >>= 1) {
        p.x += __shfl_xor(p.x, off);
        p.y += __shfl_xor(p.y, off);
        p.z += __shfl_xor(p.z, off);
        p.w += __shfl_xor(p.w, off);
    }
    float esq = (q == 0) ? p.x : (q == 1) ? p.y : (q == 2) ? p.z : p.w;
    float rinv = (end > start) ? (1.0f / esq) : 0.f;

    // Phase B: 4-way ILP, serial over edges (uniform), lane c = component c
    float a0 = 0.f, a1 = 0.f, a2 = 0.f, a3 = 0.f;
    unsigned i = start;
    for (; i + 4 <= end; i += 4) {
        unsigned sp0 = src_packed[i + 0], sp1 = src_packed[i + 1];
        unsigned sp2 = src_packed[i + 2], sp3 = src_packed[i + 3];
        unsigned s0 = sp0 & 0x3FFFFFFFu, s1 = sp1 & 0x3FFFFFFFu;
        unsigned s2 = sp2 & 0x3FFFFFFFu, s3 = sp3 & 0x3FFFFFFFu;
        unsigned c0 = sp0 >> 30, c1 = sp1 >> 30, c2 = sp2 >> 30, c3 = sp3 >> 30;
        float g0 = (c0 == 0u) ? 1.f : (c0 == 1u ? -1.f : 0.f);
        float g1 = (c1 == 0u) ? 1.f : (c1 == 1u ? -1.f : 0.f);
        float g2 = (c2 == 0u) ? 1.f : (c2 == 1u ? -1.f : 0.f);
        float g3 = (c3 == 0u) ? 1.f : (c3 == 1u ? -1.f : 0.f);
        float h0 = __half2float(hp[((size_t)s0 << 6) | (unsigned)lane]);
        float h1 = __half2float(hp[((size_t)s1 << 6) | (unsigned)lane]);
        float h2 = __half2float(hp[((size_t)s2 << 6) | (unsigned)lane]);
        float h3 = __half2float(hp[((size_t)s3 << 6) | (unsigned)lane]);
        float as0 = a_src[s0 * HEADS + q], as1 = a_src[s1 * HEADS + q];
        float as2 = a_src[s2 * HEADS + q], as3 = a_src[s3 * HEADS + q];
        float ap0 = fmaf(g0, as0, adq) + ba;
        float ap1 = fmaf(g1, as1, adq) + ba;
        float ap2 = fmaf(g2, as2, adq) + ba;
        float ap3 = fmaf(g3, as3, adq) + ba;
        float e0 = expf(ap0 > 0.f ? ap0 : 0.01f * ap0);
        float e1 = expf(ap1 > 0.f ? ap1 : 0.01f * ap1);
        float e2 = expf(ap2 > 0.f ? ap2 : 0.01f * ap2);
        float e3 = expf(ap3 > 0.f ? ap3 : 0.01f * ap3);
        a0 = fmaf(e0 * g0, h0, a0);
        a1 = fmaf(e1 * g1, h1, a1);
        a2 = fmaf(e2 * g2, h2, a2);
        a3 = fmaf(e3 * g3, h3, a3);
    }
    for (; i < end; i++) {
        unsigned sp = src_packed[i];
        unsigned s = sp & 0x3FFFFFFFu;
        unsigned c = sp >> 30;
        float g = (c == 0u) ? 1.f : (c == 1u ? -1.f : 0.f);
        float hvv = __half2float(hp[((size_t)s << 6) | (unsigned)lane]);
        float asv = a_src[s * HEADS + q];
        float ap = fmaf(g, asv, adq) + ba;
        float ev = expf(ap > 0.f ? ap : 0.01f * ap);
        a0 = fmaf(ev * g, hvv, a0);
    }
    out[((size_t)d << 6) | (unsigned)lane] = ((a0 + a1) + (a2 + a3)) * rinv;
}

// ---------------------------------------------------------------------------
extern "C" void kernel_launch(void* const* d_in, const int* in_sizes, int n_in,
                              void* d_out, int out_size, void* d_ws, size_t ws_size,
                              hipStream_t stream)
{
    const float* h       = (const float*)d_in[0];
    const int*   src_idx = (const int*)d_in[1];
    const int*   dst_idx = (const int*)d_in[2];
    const float* W_w     = (const float*)d_in[3];
    const float* b_w     = (const float*)d_in[4];
    const float* W_a     = (const float*)d_in[5];
    const float* b_a     = (const float*)d_in[6];
    const float* W_d     = (const float*)d_in[7];
    const float* b_d     = (const float*)d_in[8];
    const float* W_f     = (const float*)d_in[9];
    const float* b_f     = (const float*)d_in[10];

    int N = in_sizes[0] / F;
    int E = in_sizes[1];
    int nb = (N + 255) / 256;

    char* ws = (char*)d_ws;
    float*    tfeat = (float*)ws;      ws += (size_t)N * F * 4;        // 12.8MB
    __half*   hp    = (__half*)ws;     ws += (size_t)N * F * 2;        // 6.4MB
    double*   u_arr = (double*)ws;     ws += (size_t)N * 8;            // 0.4MB
    double*   v_arr = (double*)ws;     ws += (size_t)N * 8;            // 0.4MB
    float*    a_src = (float*)ws;      ws += (size_t)N * HEADS * 4;    // 0.8MB
    float*    a_dst = (float*)ws;      ws += (size_t)N * HEADS * 4;    // 0.8MB
    unsigned* cnt   = (unsigned*)ws;   ws += (size_t)N * 4;            // 0.2MB
    unsigned* rowptr= (unsigned*)ws;   ws += ((size_t)N + 4) * 4;      // 0.2MB
    unsigned* bsum  = (unsigned*)ws;   ws += 1024;                     // 1KB
    unsigned* pc    = (unsigned*)ws;   ws += (size_t)E * 4;            // 4MB
    unsigned* src_p = (unsigned*)ws;   ws += (size_t)E * 4;            // 4MB

    float* out = (float*)d_out;

    hipMemsetAsync(cnt, 0, (size_t)N * sizeof(unsigned), stream);

    node_kernel<<<2 * nb, 256, 0, stream>>>(
        h, W_w, b_w, W_a, W_d, b_d, W_f, tfeat, hp, u_arr, v_arr, a_src, a_dst,
        N, nb);

    count_sign_kernel<<<(E + 255) / 256, 256, 0, stream>>>(
        src_idx, dst_idx, u_arr, v_arr, tfeat, W_f, b_f, cnt, pc, E);

    scan1_kernel<<<nb, 256, 0, stream>>>(cnt, rowptr, bsum, N);
    scan2_kernel<<<1, 256, 0, stream>>>(bsum, nb);
    scan3_kernel<<<nb, 256, 0, stream>>>(rowptr, bsum, N, E);

    place_kernel<<<(E + 255) / 256, 256, 0, stream>>>(
        src_idx, dst_idx, pc, rowptr, src_p, E);

    dst_gather_kernel<<<(N * 64 + 255) / 256, 256, 0, stream>>>(
        rowptr, src_p, a_src, a_dst, b_a, hp, out, N);
}

// Round 8
// 162.524 us; speedup vs baseline: 2.9572x; 1.1196x over previous
//
#include <hip/hip_runtime.h>
#include <hip/hip_fp16.h>

constexpr int F  = 64;   // IN_FEATS == ATT_HEADS*H_FEATS
constexpr int HEADS = 4;
constexpr int CAP = 256; // per-wave LDS weight slots in dst_gather

// ---------------------------------------------------------------------------
// Pass 1 (per node), fp32 mirroring numpy BLAS (seq-k FMA from 0, bias after).
// Blocks [0,nb): W_d path (tfeat fp32, u/v f64). Blocks [nb,2nb): W_w path
// (hp as fp16, a_src/a_dst fp32). W transposed in LDS -> ds_read_b128.
// ---------------------------------------------------------------------------
__global__ __launch_bounds__(256) void node_kernel(
    const float* __restrict__ h,
    const float* __restrict__ W_w, const float* __restrict__ b_w,
    const float* __restrict__ W_a,
    const float* __restrict__ W_d, const float* __restrict__ b_d,
    const float* __restrict__ W_f,
    float* __restrict__ tfeat, __half* __restrict__ hp,
    double* __restrict__ u_arr, double* __restrict__ v_arr,
    float* __restrict__ a_src, float* __restrict__ a_dst, int N, int nb)
{
    __shared__ float sWT[F * F];     // [j][k] transposed
    __shared__ float sb[F];
    __shared__ double swfA[F], swfB[F];
    __shared__ float sWa[32];

    int tid = threadIdx.x;
    bool isW = blockIdx.x >= nb;     // W_w path?
    const float* Wsrc = isW ? W_w : W_d;
    for (int i = tid; i < F * F; i += 256) {
        int k = i >> 6, j = i & 63;
        sWT[j * F + k] = Wsrc[i];
    }
    if (tid < F) sb[tid] = isW ? b_w[tid] : b_d[tid];
    if (!isW && tid < F) {
        swfA[tid] = (double)W_f[tid] + (double)W_f[2 * F + tid];
        swfB[tid] = (double)W_f[F + tid] - (double)W_f[2 * F + tid];
    }
    if (isW && tid < 32) sWa[tid] = W_a[tid];
    __syncthreads();

    int blk = isW ? (blockIdx.x - nb) : blockIdx.x;
    int n = blk * 256 + tid;
    if (n >= N) return;

    float4 hv[16];
    const float4* h4 = reinterpret_cast<const float4*>(h + (size_t)n * F);
#pragma unroll
    for (int i = 0; i < 16; i++) hv[i] = h4[i];

    if (!isW) {
        // ---- W_d path: tfeat row + u,v (f64, j-sequential) ----
        double u = 0.0, v = 0.0;
        float4 tq;
        float4* trow = reinterpret_cast<float4*>(tfeat + (size_t)n * F);
#pragma unroll 4
        for (int j = 0; j < F; j++) {
            const float4* row = reinterpret_cast<const float4*>(&sWT[j * F]);
            float t = 0.f;
#pragma unroll
            for (int kk = 0; kk < 16; kk++) {
                float4 w = row[kk];
                float4 x = hv[kk];
                t = fmaf(x.x, w.x, t);
                t = fmaf(x.y, w.y, t);
                t = fmaf(x.z, w.z, t);
                t = fmaf(x.w, w.w, t);
            }
            t = t + sb[j];
            u = fma((double)t, swfA[j], u);
            v = fma((double)t, swfB[j], v);
            if ((j & 3) == 0) tq.x = t;
            else if ((j & 3) == 1) tq.y = t;
            else if ((j & 3) == 2) tq.z = t;
            else { tq.w = t; trow[j >> 2] = tq; }
        }
        u_arr[n] = u;
        v_arr[n] = v;
    } else {
        // ---- W_w path: hp row (fp16) + a_src,a_dst per head ----
        __half2* prow = reinterpret_cast<__half2*>(hp + (size_t)n * F);
#pragma unroll
        for (int qh = 0; qh < 4; qh++) {
            float asq = 0.f, adq = 0.f;
            float pprev = 0.f;
#pragma unroll 4
            for (int jj = 0; jj < 16; jj++) {
                int j = qh * 16 + jj;
                const float4* row = reinterpret_cast<const float4*>(&sWT[j * F]);
                float p = 0.f;
#pragma unroll
                for (int kk = 0; kk < 16; kk++) {
                    float4 w = row[kk];
                    float4 x = hv[kk];
                    p = fmaf(x.x, w.x, p);
                    p = fmaf(x.y, w.y, p);
                    p = fmaf(x.z, w.z, p);
                    p = fmaf(x.w, w.w, p);
                }
                p = p + sb[j];
                asq = fmaf(p, sWa[jj], asq);
                adq = fmaf(p, sWa[16 + jj], adq);
                if ((jj & 1) == 0) pprev = p;
                else prow[j >> 1] = __floats2half2_rn(pprev, p);
            }
            a_src[n * HEADS + qh] = asq;
            a_dst[n * HEADS + qh] = adq;
        }
    }
}

// ---------------------------------------------------------------------------
// Tier-2 sign fallback: literal fp32 192-term sequential FMA in the
// reference's e_feat section order (rare: |f64 margin| < 1e-4).
// ---------------------------------------------------------------------------
__device__ __noinline__ float tier2_sign(
    const float* __restrict__ tfeat, const float* __restrict__ sWf,
    int s, int d, float bf)
{
    const float4* ts = reinterpret_cast<const float4*>(tfeat + (size_t)s * F);
    const float4* td = reinterpret_cast<const float4*>(tfeat + (size_t)d * F);
    float sv[F];
#pragma unroll
    for (int i = 0; i < 16; i++) {
        float4 a = ts[i];
        sv[4 * i + 0] = a.x; sv[4 * i + 1] = a.y;
        sv[4 * i + 2] = a.z; sv[4 * i + 3] = a.w;
    }
    float acc = 0.f;
#pragma unroll
    for (int j = 0; j < F; j++) acc = fmaf(sv[j], sWf[j], acc);
#pragma unroll
    for (int i = 0; i < 16; i++) {
        float4 a = td[i];
        acc = fmaf(a.x, sWf[F + 4 * i + 0], acc);
        acc = fmaf(a.y, sWf[F + 4 * i + 1], acc);
        acc = fmaf(a.z, sWf[F + 4 * i + 2], acc);
        acc = fmaf(a.w, sWf[F + 4 * i + 3], acc);
    }
#pragma unroll
    for (int i = 0; i < 16; i++) {
        float4 a = td[i];
        acc = fmaf(sv[4 * i + 0] - a.x, sWf[2 * F + 4 * i + 0], acc);
        acc = fmaf(sv[4 * i + 1] - a.y, sWf[2 * F + 4 * i + 1], acc);
        acc = fmaf(sv[4 * i + 2] - a.z, sWf[2 * F + 4 * i + 2], acc);
        acc = fmaf(sv[4 * i + 3] - a.w, sWf[2 * F + 4 * i + 3], acc);
    }
    float sp = acc + bf;
    return (sp > 0.f) ? 1.f : (sp < 0.f ? -1.f : 0.f);
}

// ---------------------------------------------------------------------------
// CSR step 1 + sign: pos[e] = atomicAdd(cnt[dst],1); sign per edge (f64 tier1,
// literal tier2). pc[e] = pos | code<<30   (coalesced 4B store by e).
// ---------------------------------------------------------------------------
__global__ __launch_bounds__(256) void count_sign_kernel(
    const int* __restrict__ src_idx, const int* __restrict__ dst_idx,
    const double* __restrict__ u_arr, const double* __restrict__ v_arr,
    const float* __restrict__ tfeat, const float* __restrict__ W_f,
    const float* __restrict__ b_f,
    unsigned* __restrict__ cnt, unsigned* __restrict__ pc, int E)
{
    __shared__ float sWf[3 * F];
    int tid = threadIdx.x;
    if (tid < 3 * F) sWf[tid] = W_f[tid];
    __syncthreads();

    int e = blockIdx.x * 256 + tid;
    if (e >= E) return;

    int s = src_idx[e], d = dst_idx[e];
    float bf = b_f[0];

    unsigned pos = atomicAdd(&cnt[d], 1u);      // independent of sign chain

    double m = u_arr[s] + v_arr[d] + (double)bf;
    float sgn = (fabs(m) >= 1e-4) ? ((m > 0.0) ? 1.f : -1.f)
                                  : tier2_sign(tfeat, sWf, s, d, bf);
    unsigned code = (sgn > 0.f) ? 0u : (sgn < 0.f ? 1u : 2u);
    pc[e] = pos | (code << 30);
}

// ---------------------------------------------------------------------------
// CSR step 2a/2b/2c: hierarchical exclusive scan -> rowptr
// ---------------------------------------------------------------------------
__global__ __launch_bounds__(256) void scan1_kernel(
    const unsigned* __restrict__ cnt, unsigned* __restrict__ rowptr,
    unsigned* __restrict__ bsum, int N)
{
    int t = threadIdx.x;
    int i = blockIdx.x * 256 + t;
    unsigned v = (i < N) ? cnt[i] : 0u;
    unsigned x = v;
#pragma unroll
    for (int off = 1; off < 64; off <<= 1) {
        unsigned y = __shfl_up(x, off);
        if ((t & 63) >= off) x += y;
    }
    __shared__ unsigned wsum[4];
    if ((t & 63) == 63) wsum[t >> 6] = x;
    __syncthreads();
    unsigned pre = 0;
#pragma unroll
    for (int w = 0; w < 3; w++) if (w < (t >> 6)) pre += wsum[w];
    unsigned incl = x + pre;
    if (i < N) rowptr[i] = incl - v;
    if (t == 255) bsum[blockIdx.x] = incl;
}

__global__ __launch_bounds__(256) void scan2_kernel(unsigned* __restrict__ bsum, int nb)
{
    int t = threadIdx.x;
    unsigned v = (t < nb) ? bsum[t] : 0u;
    unsigned x = v;
#pragma unroll
    for (int off = 1; off < 64; off <<= 1) {
        unsigned y = __shfl_up(x, off);
        if ((t & 63) >= off) x += y;
    }
    __shared__ unsigned wsum[4];
    if ((t & 63) == 63) wsum[t >> 6] = x;
    __syncthreads();
    unsigned pre = 0;
#pragma unroll
    for (int w = 0; w < 3; w++) if (w < (t >> 6)) pre += wsum[w];
    if (t < nb) bsum[t] = x + pre - v;
}

__global__ __launch_bounds__(256) void scan3_kernel(
    unsigned* __restrict__ rowptr, const unsigned* __restrict__ bsum, int N, int E)
{
    int i = blockIdx.x * 256 + threadIdx.x;
    if (i < N) rowptr[i] += bsum[blockIdx.x];
    if (i == 0) rowptr[N] = (unsigned)E;
}

// ---------------------------------------------------------------------------
// CSR step 3: pure placement. 4B scattered store per edge, no atomics.
// ---------------------------------------------------------------------------
__global__ __launch_bounds__(256) void place_kernel(
    const int* __restrict__ src_idx, const int* __restrict__ dst_idx,
    const unsigned* __restrict__ pc, const unsigned* __restrict__ rowptr,
    unsigned* __restrict__ src_packed, int E)
{
    int e = blockIdx.x * 256 + threadIdx.x;
    if (e >= E) return;
    unsigned p = pc[e];
    unsigned pos = p & 0x3FFFFFFFu;
    unsigned code = p & 0xC0000000u;
    int d = dst_idx[e];
    src_packed[rowptr[d] + pos] = (unsigned)src_idx[e] | code;
}

// ---------------------------------------------------------------------------
// Pass 4: one wave per dst. Phase A (edge-parallel): compute 4 signed weights
// sgn*ex once per edge, stash in per-wave LDS, accumulate esum; butterfly.
// Barrier. Phase B: per edge, broadcast ds_read of this lane's head weight +
// fp16 hp load + fmaf. Normalize once by rinv. One 256B store per dst.
// ---------------------------------------------------------------------------
__global__ __launch_bounds__(256) void dst_gather_kernel(
    const unsigned* __restrict__ rowptr,
    const unsigned* __restrict__ src_packed,
    const float* __restrict__ a_src, const float* __restrict__ a_dst,
    const float* __restrict__ b_a,
    const __half* __restrict__ hp,
    float* __restrict__ out, int N)
{
    __shared__ float sw[4][CAP * 4];   // [wave][slot*4+head] = sgn*ex

    int tid = threadIdx.x;
    int wslot = tid >> 6;
    int lane = tid & 63;
    int q = lane >> 4;
    int d = (blockIdx.x * 256 + tid) >> 6;
    bool valid = d < N;

    unsigned start = 0, end = 0;
    float ba = b_a[0];
    float4 ad4 = make_float4(0.f, 0.f, 0.f, 0.f);
    if (valid) {
        start = rowptr[d];
        end = rowptr[d + 1];
        ad4 = *reinterpret_cast<const float4*>(a_dst + (size_t)d * HEADS);
    }
    float adq = (q == 0) ? ad4.x : (q == 1) ? ad4.y : (q == 2) ? ad4.z : ad4.w;

    // Phase A: per-lane edges, all 4 heads each; stash sgn*ex in LDS
    float4 p = make_float4(0.f, 0.f, 0.f, 0.f);
    if (valid) {
        for (unsigned i = start + lane; i < end; i += 64) {
            unsigned sp = src_packed[i];
            unsigned s = sp & 0x3FFFFFFFu;
            unsigned c = sp >> 30;
            float sgn = (c == 0u) ? 1.f : (c == 1u ? -1.f : 0.f);
            float4 as4 = *reinterpret_cast<const float4*>(a_src + (size_t)s * HEADS);
            float ap0 = fmaf(sgn, as4.x, ad4.x) + ba;
            float ap1 = fmaf(sgn, as4.y, ad4.y) + ba;
            float ap2 = fmaf(sgn, as4.z, ad4.z) + ba;
            float ap3 = fmaf(sgn, as4.w, ad4.w) + ba;
            float e0 = expf(ap0 > 0.f ? ap0 : 0.01f * ap0);
            float e1 = expf(ap1 > 0.f ? ap1 : 0.01f * ap1);
            float e2 = expf(ap2 > 0.f ? ap2 : 0.01f * ap2);
            float e3 = expf(ap3 > 0.f ? ap3 : 0.01f * ap3);
            p.x += e0; p.y += e1; p.z += e2; p.w += e3;
            unsigned slot = i - start;
            if (slot < CAP) {
                float4* dst4 = reinterpret_cast<float4*>(&sw[wslot][slot * 4]);
                *dst4 = make_float4(sgn * e0, sgn * e1, sgn * e2, sgn * e3);
            }
        }
    }
    __syncthreads();   // LDS weights visible to all lanes

#pragma unroll
    for (int off = 32; off >= 1; off >>= 1) {
        p.x += __shfl_xor(p.x, off);
        p.y += __shfl_xor(p.y, off);
        p.z += __shfl_xor(p.z, off);
        p.w += __shfl_xor(p.w, off);
    }
    if (!valid) return;

    float esq = (q == 0) ? p.x : (q == 1) ? p.y : (q == 2) ? p.z : p.w;
    float rinv = (end > start) ? (1.0f / esq) : 0.f;

    const float* swb = &sw[wslot][0];
    unsigned cend = min(end, start + CAP);

    // Phase B: 4-way ILP over LDS-cached weights
    float a0 = 0.f, a1 = 0.f, a2 = 0.f, a3 = 0.f;
    unsigned i = start;
    for (; i + 4 <= cend; i += 4) {
        unsigned t0 = i - start;
        float w0 = swb[(t0 + 0) * 4 + q];
        float w1 = swb[(t0 + 1) * 4 + q];
        float w2 = swb[(t0 + 2) * 4 + q];
        float w3 = swb[(t0 + 3) * 4 + q];
        unsigned s0 = src_packed[i + 0] & 0x3FFFFFFFu;
        unsigned s1 = src_packed[i + 1] & 0x3FFFFFFFu;
        unsigned s2 = src_packed[i + 2] & 0x3FFFFFFFu;
        unsigned s3 = src_packed[i + 3] & 0x3FFFFFFFu;
        float h0 = __half2float(hp[((size_t)s0 << 6) | (unsigned)lane]);
        float h1 = __half2float(hp[((size_t)s1 << 6) | (unsigned)lane]);
        float h2 = __half2float(hp[((size_t)s2 << 6) | (unsigned)lane]);
        float h3 = __half2float(hp[((size_t)s3 << 6) | (unsigned)lane]);
        a0 = fmaf(w0, h0, a0);
        a1 = fmaf(w1, h1, a1);
        a2 = fmaf(w2, h2, a2);
        a3 = fmaf(w3, h3, a3);
    }
    for (; i < cend; i++) {
        float w = swb[(i - start) * 4 + q];
        unsigned s = src_packed[i] & 0x3FFFFFFFu;
        a0 = fmaf(w, __half2float(hp[((size_t)s << 6) | (unsigned)lane]), a0);
    }
    // fallback: degree > CAP (essentially never for Poisson(20); correct always)
    for (; i < end; i++) {
        unsigned sp = src_packed[i];
        unsigned s = sp & 0x3FFFFFFFu;
        unsigned c = sp >> 30;
        float g = (c == 0u) ? 1.f : (c == 1u ? -1.f : 0.f);
        float asv = a_src[s * HEADS + q];
        float ap = fmaf(g, asv, adq) + ba;
        float ev = expf(ap > 0.f ? ap : 0.01f * ap);
        a0 = fmaf(ev * g, __half2float(hp[((size_t)s << 6) | (unsigned)lane]), a0);
    }
    out[((size_t)d << 6) | (unsigned)lane] = ((a0 + a1) + (a2 + a3)) * rinv;
}

// ---------------------------------------------------------------------------
extern "C" void kernel_launch(void* const* d_in, const int* in_sizes, int n_in,
                              void* d_out, int out_size, void* d_ws, size_t ws_size,
                              hipStream_t stream)
{
    const float* h       = (const float*)d_in[0];
    const int*   src_idx = (const int*)d_in[1];
    const int*   dst_idx = (const int*)d_in[2];
    const float* W_w     = (const float*)d_in[3];
    const float* b_w     = (const float*)d_in[4];
    const float* W_a     = (const float*)d_in[5];
    const float* b_a     = (const float*)d_in[6];
    const float* W_d     = (const float*)d_in[7];
    const float* b_d     = (const float*)d_in[8];
    const float* W_f     = (const float*)d_in[9];
    const float* b_f     = (const float*)d_in[10];

    int N = in_sizes[0] / F;
    int E = in_sizes[1];
    int nb = (N + 255) / 256;

    char* ws = (char*)d_ws;
    float*    tfeat = (float*)ws;      ws += (size_t)N * F * 4;        // 12.8MB
    __half*   hp    = (__half*)ws;     ws += (size_t)N * F * 2;        // 6.4MB
    double*   u_arr = (double*)ws;     ws += (size_t)N * 8;            // 0.4MB
    double*   v_arr = (double*)ws;     ws += (size_t)N * 8;            // 0.4MB
    float*    a_src = (float*)ws;      ws += (size_t)N * HEADS * 4;    // 0.8MB
    float*    a_dst = (float*)ws;      ws += (size_t)N * HEADS * 4;    // 0.8MB
    unsigned* cnt   = (unsigned*)ws;   ws += (size_t)N * 4;            // 0.2MB
    unsigned* rowptr= (unsigned*)ws;   ws += ((size_t)N + 4) * 4;      // 0.2MB
    unsigned* bsum  = (unsigned*)ws;   ws += 1024;                     // 1KB
    unsigned* pc    = (unsigned*)ws;   ws += (size_t)E * 4;            // 4MB
    unsigned* src_p = (unsigned*)ws;   ws += (size_t)E * 4;            // 4MB

    float* out = (float*)d_out;

    hipMemsetAsync(cnt, 0, (size_t)N * sizeof(unsigned), stream);

    node_kernel<<<2 * nb, 256, 0, stream>>>(
        h, W_w, b_w, W_a, W_d, b_d, W_f, tfeat, hp, u_arr, v_arr, a_src, a_dst,
        N, nb);

    count_sign_kernel<<<(E + 255) / 256, 256, 0, stream>>>(
        src_idx, dst_idx, u_arr, v_arr, tfeat, W_f, b_f, cnt, pc, E);

    scan1_kernel<<<nb, 256, 0, stream>>>(cnt, rowptr, bsum, N);
    scan2_kernel<<<1, 256, 0, stream>>>(bsum, nb);
    scan3_kernel<<<nb, 256, 0, stream>>>(rowptr, bsum, N, E);

    place_kernel<<<(E + 255) / 256, 256, 0, stream>>>(
        src_idx, dst_idx, pc, rowptr, src_p, E);

    dst_gather_kernel<<<(N * 64 + 255) / 256, 256, 0, stream>>>(
        rowptr, src_p, a_src, a_dst, b_a, hp, out, N);
}

// Round 9
// 146.671 us; speedup vs baseline: 3.2768x; 1.1081x over previous
//
#include <hip/hip_runtime.h>
#include <hip/hip_fp16.h>

constexpr int F  = 64;   // IN_FEATS == ATT_HEADS*H_FEATS
constexpr int HEADS = 4;
constexpr int CAP = 256; // per-wave LDS slots in dst_gather

// ---------------------------------------------------------------------------
// Pass 1 (per node), fp32 mirroring numpy BLAS (seq-k FMA from 0, bias after).
// Blocks [0,nb): W_d path (tfeat fp32, u/v f64) + zero cnt. Blocks [nb,2nb):
// W_w path (hp fp16, a_src/a_dst fp32). W transposed in LDS -> ds_read_b128.
// ---------------------------------------------------------------------------
__global__ __launch_bounds__(256) void node_kernel(
    const float* __restrict__ h,
    const float* __restrict__ W_w, const float* __restrict__ b_w,
    const float* __restrict__ W_a,
    const float* __restrict__ W_d, const float* __restrict__ b_d,
    const float* __restrict__ W_f,
    float* __restrict__ tfeat, __half* __restrict__ hp,
    double* __restrict__ u_arr, double* __restrict__ v_arr,
    float* __restrict__ a_src, float* __restrict__ a_dst,
    unsigned* __restrict__ cnt, int N, int nb)
{
    __shared__ float sWT[F * F];     // [j][k] transposed
    __shared__ float sb[F];
    __shared__ double swfA[F], swfB[F];
    __shared__ float sWa[32];

    int tid = threadIdx.x;
    bool isW = blockIdx.x >= nb;     // W_w path?
    const float* Wsrc = isW ? W_w : W_d;
    for (int i = tid; i < F * F; i += 256) {
        int k = i >> 6, j = i & 63;
        sWT[j * F + k] = Wsrc[i];
    }
    if (tid < F) sb[tid] = isW ? b_w[tid] : b_d[tid];
    if (!isW && tid < F) {
        swfA[tid] = (double)W_f[tid] + (double)W_f[2 * F + tid];
        swfB[tid] = (double)W_f[F + tid] - (double)W_f[2 * F + tid];
    }
    if (isW && tid < 32) sWa[tid] = W_a[tid];
    __syncthreads();

    int blk = isW ? (blockIdx.x - nb) : blockIdx.x;
    int n = blk * 256 + tid;
    if (n >= N) return;

    if (!isW) cnt[n] = 0;            // replaces the memset dispatch

    float4 hv[16];
    const float4* h4 = reinterpret_cast<const float4*>(h + (size_t)n * F);
#pragma unroll
    for (int i = 0; i < 16; i++) hv[i] = h4[i];

    if (!isW) {
        // ---- W_d path: tfeat row + u,v (f64, j-sequential) ----
        double u = 0.0, v = 0.0;
        float4 tq;
        float4* trow = reinterpret_cast<float4*>(tfeat + (size_t)n * F);
#pragma unroll 4
        for (int j = 0; j < F; j++) {
            const float4* row = reinterpret_cast<const float4*>(&sWT[j * F]);
            float t = 0.f;
#pragma unroll
            for (int kk = 0; kk < 16; kk++) {
                float4 w = row[kk];
                float4 x = hv[kk];
                t = fmaf(x.x, w.x, t);
                t = fmaf(x.y, w.y, t);
                t = fmaf(x.z, w.z, t);
                t = fmaf(x.w, w.w, t);
            }
            t = t + sb[j];
            u = fma((double)t, swfA[j], u);
            v = fma((double)t, swfB[j], v);
            if ((j & 3) == 0) tq.x = t;
            else if ((j & 3) == 1) tq.y = t;
            else if ((j & 3) == 2) tq.z = t;
            else { tq.w = t; trow[j >> 2] = tq; }
        }
        u_arr[n] = u;
        v_arr[n] = v;
    } else {
        // ---- W_w path: hp row (fp16) + a_src,a_dst per head ----
        __half2* prow = reinterpret_cast<__half2*>(hp + (size_t)n * F);
#pragma unroll
        for (int qh = 0; qh < 4; qh++) {
            float asq = 0.f, adq = 0.f;
            float pprev = 0.f;
#pragma unroll 4
            for (int jj = 0; jj < 16; jj++) {
                int j = qh * 16 + jj;
                const float4* row = reinterpret_cast<const float4*>(&sWT[j * F]);
                float p = 0.f;
#pragma unroll
                for (int kk = 0; kk < 16; kk++) {
                    float4 w = row[kk];
                    float4 x = hv[kk];
                    p = fmaf(x.x, w.x, p);
                    p = fmaf(x.y, w.y, p);
                    p = fmaf(x.z, w.z, p);
                    p = fmaf(x.w, w.w, p);
                }
                p = p + sb[j];
                asq = fmaf(p, sWa[jj], asq);
                adq = fmaf(p, sWa[16 + jj], adq);
                if ((jj & 1) == 0) pprev = p;
                else prow[j >> 1] = __floats2half2_rn(pprev, p);
            }
            a_src[n * HEADS + qh] = asq;
            a_dst[n * HEADS + qh] = adq;
        }
    }
}

// ---------------------------------------------------------------------------
// Tier-2 sign fallback: literal fp32 192-term sequential FMA in the
// reference's e_feat section order (rare: |f64 margin| < 1e-4).
// ---------------------------------------------------------------------------
__device__ __noinline__ float tier2_sign(
    const float* __restrict__ tfeat, const float* __restrict__ sWf,
    int s, int d, float bf)
{
    const float4* ts = reinterpret_cast<const float4*>(tfeat + (size_t)s * F);
    const float4* td = reinterpret_cast<const float4*>(tfeat + (size_t)d * F);
    float sv[F];
#pragma unroll
    for (int i = 0; i < 16; i++) {
        float4 a = ts[i];
        sv[4 * i + 0] = a.x; sv[4 * i + 1] = a.y;
        sv[4 * i + 2] = a.z; sv[4 * i + 3] = a.w;
    }
    float acc = 0.f;
#pragma unroll
    for (int j = 0; j < F; j++) acc = fmaf(sv[j], sWf[j], acc);
#pragma unroll
    for (int i = 0; i < 16; i++) {
        float4 a = td[i];
        acc = fmaf(a.x, sWf[F + 4 * i + 0], acc);
        acc = fmaf(a.y, sWf[F + 4 * i + 1], acc);
        acc = fmaf(a.z, sWf[F + 4 * i + 2], acc);
        acc = fmaf(a.w, sWf[F + 4 * i + 3], acc);
    }
#pragma unroll
    for (int i = 0; i < 16; i++) {
        float4 a = td[i];
        acc = fmaf(sv[4 * i + 0] - a.x, sWf[2 * F + 4 * i + 0], acc);
        acc = fmaf(sv[4 * i + 1] - a.y, sWf[2 * F + 4 * i + 1], acc);
        acc = fmaf(sv[4 * i + 2] - a.z, sWf[2 * F + 4 * i + 2], acc);
        acc = fmaf(sv[4 * i + 3] - a.w, sWf[2 * F + 4 * i + 3], acc);
    }
    float sp = acc + bf;
    return (sp > 0.f) ? 1.f : (sp < 0.f ? -1.f : 0.f);
}

// ---------------------------------------------------------------------------
// CSR step 1 + sign: 2 edges/thread, independent chains, early atomics.
// pc[e] = pos | code<<30  (coalesced 4B store by e).
// ---------------------------------------------------------------------------
__global__ __launch_bounds__(256) void count_sign_kernel(
    const int* __restrict__ src_idx, const int* __restrict__ dst_idx,
    const double* __restrict__ u_arr, const double* __restrict__ v_arr,
    const float* __restrict__ tfeat, const float* __restrict__ W_f,
    const float* __restrict__ b_f,
    unsigned* __restrict__ cnt, unsigned* __restrict__ pc, int E)
{
    __shared__ float sWf[3 * F];
    int tid = threadIdx.x;
    if (tid < 3 * F) sWf[tid] = W_f[tid];
    __syncthreads();

    float bf = b_f[0];
    int e0 = blockIdx.x * 512 + tid;
    int e1 = e0 + 256;
    bool ok0 = e0 < E, ok1 = e1 < E;

    int s0 = 0, d0 = 0, s1 = 0, d1 = 0;
    if (ok0) { s0 = src_idx[e0]; d0 = dst_idx[e0]; }
    if (ok1) { s1 = src_idx[e1]; d1 = dst_idx[e1]; }

    unsigned p0 = ok0 ? atomicAdd(&cnt[d0], 1u) : 0u;
    unsigned p1 = ok1 ? atomicAdd(&cnt[d1], 1u) : 0u;

    double us0 = ok0 ? u_arr[s0] : 0.0, vd0 = ok0 ? v_arr[d0] : 0.0;
    double us1 = ok1 ? u_arr[s1] : 0.0, vd1 = ok1 ? v_arr[d1] : 0.0;
    double m0 = us0 + vd0 + (double)bf;
    double m1 = us1 + vd1 + (double)bf;

    float sg0 = (fabs(m0) >= 1e-4) ? ((m0 > 0.0) ? 1.f : -1.f)
                                   : (ok0 ? tier2_sign(tfeat, sWf, s0, d0, bf) : 0.f);
    float sg1 = (fabs(m1) >= 1e-4) ? ((m1 > 0.0) ? 1.f : -1.f)
                                   : (ok1 ? tier2_sign(tfeat, sWf, s1, d1, bf) : 0.f);

    if (ok0) {
        unsigned c0 = (sg0 > 0.f) ? 0u : (sg0 < 0.f ? 1u : 2u);
        pc[e0] = p0 | (c0 << 30);
    }
    if (ok1) {
        unsigned c1 = (sg1 > 0.f) ? 0u : (sg1 < 0.f ? 1u : 2u);
        pc[e1] = p1 | (c1 << 30);
    }
}

// ---------------------------------------------------------------------------
// CSR scan: scan1 (per-256-chunk local scan + chunk totals), scan3 (per-block
// reduce of preceding chunk totals + add + rowptr[N]).
// ---------------------------------------------------------------------------
__global__ __launch_bounds__(256) void scan1_kernel(
    const unsigned* __restrict__ cnt, unsigned* __restrict__ rowptr,
    unsigned* __restrict__ bsum, int N)
{
    int t = threadIdx.x;
    int i = blockIdx.x * 256 + t;
    unsigned v = (i < N) ? cnt[i] : 0u;
    unsigned x = v;
#pragma unroll
    for (int off = 1; off < 64; off <<= 1) {
        unsigned y = __shfl_up(x, off);
        if ((t & 63) >= off) x += y;
    }
    __shared__ unsigned wsum[4];
    if ((t & 63) == 63) wsum[t >> 6] = x;
    __syncthreads();
    unsigned pre = 0;
#pragma unroll
    for (int w = 0; w < 3; w++) if (w < (t >> 6)) pre += wsum[w];
    unsigned incl = x + pre;
    if (i < N) rowptr[i] = incl - v;
    if (t == 255) bsum[blockIdx.x] = incl;
}

__global__ __launch_bounds__(256) void scan3_kernel(
    unsigned* __restrict__ rowptr, const unsigned* __restrict__ bsum,
    int N, int E, int nb)
{
    int t = threadIdx.x;
    int lim = min((int)blockIdx.x, nb);
    unsigned v = 0;
    for (int w = t; w < lim; w += 256) v += bsum[w];
#pragma unroll
    for (int off = 32; off >= 1; off >>= 1) v += __shfl_xor(v, off);
    __shared__ unsigned ws[4];
    if ((t & 63) == 0) ws[t >> 6] = v;
    __syncthreads();
    unsigned prefix = ws[0] + ws[1] + ws[2] + ws[3];

    int i = blockIdx.x * 256 + t;
    if (i < N) rowptr[i] += prefix;
    if (i == 0) rowptr[N] = (unsigned)E;
}

// ---------------------------------------------------------------------------
// CSR step 3: pure placement. 4B scattered store per edge, no atomics.
// ---------------------------------------------------------------------------
__global__ __launch_bounds__(256) void place_kernel(
    const int* __restrict__ src_idx, const int* __restrict__ dst_idx,
    const unsigned* __restrict__ pc, const unsigned* __restrict__ rowptr,
    unsigned* __restrict__ src_packed, int E)
{
    int e = blockIdx.x * 256 + threadIdx.x;
    if (e >= E) return;
    unsigned p = pc[e];
    unsigned pos = p & 0x3FFFFFFFu;
    unsigned code = p & 0xC0000000u;
    int d = dst_idx[e];
    src_packed[rowptr[d] + pos] = (unsigned)src_idx[e] | code;
}

// ---------------------------------------------------------------------------
// Pass 4: one wave per dst. Phase A: compute 4 signed weights sgn*ex once per
// edge + stash {weights, src} in LDS + esum; butterfly. Phase B: 8-way ILP,
// LDS-fed (no global re-reads on the address chain), fp16 hp gather, one
// normalize, one 256B store.
// ---------------------------------------------------------------------------
__global__ __launch_bounds__(256) void dst_gather_kernel(
    const unsigned* __restrict__ rowptr,
    const unsigned* __restrict__ src_packed,
    const float* __restrict__ a_src, const float* __restrict__ a_dst,
    const float* __restrict__ b_a,
    const __half* __restrict__ hp,
    float* __restrict__ out, int N)
{
    __shared__ float sw[4][CAP * 4];     // [wave][slot*4+head] = sgn*ex
    __shared__ unsigned ssrc[4][CAP];    // [wave][slot] = src index

    int tid = threadIdx.x;
    int wslot = tid >> 6;
    int lane = tid & 63;
    int q = lane >> 4;
    int d = (blockIdx.x * 256 + tid) >> 6;
    bool valid = d < N;

    unsigned start = 0, end = 0;
    float ba = b_a[0];
    float4 ad4 = make_float4(0.f, 0.f, 0.f, 0.f);
    if (valid) {
        start = rowptr[d];
        end = rowptr[d + 1];
        ad4 = *reinterpret_cast<const float4*>(a_dst + (size_t)d * HEADS);
    }
    float adq = (q == 0) ? ad4.x : (q == 1) ? ad4.y : (q == 2) ? ad4.z : ad4.w;

    // Phase A
    float4 p = make_float4(0.f, 0.f, 0.f, 0.f);
    if (valid) {
        for (unsigned i = start + lane; i < end; i += 64) {
            unsigned sp = src_packed[i];
            unsigned s = sp & 0x3FFFFFFFu;
            unsigned c = sp >> 30;
            float sgn = (c == 0u) ? 1.f : (c == 1u ? -1.f : 0.f);
            float4 as4 = *reinterpret_cast<const float4*>(a_src + (size_t)s * HEADS);
            float ap0 = fmaf(sgn, as4.x, ad4.x) + ba;
            float ap1 = fmaf(sgn, as4.y, ad4.y) + ba;
            float ap2 = fmaf(sgn, as4.z, ad4.z) + ba;
            float ap3 = fmaf(sgn, as4.w, ad4.w) + ba;
            float e0 = expf(ap0 > 0.f ? ap0 : 0.01f * ap0);
            float e1 = expf(ap1 > 0.f ? ap1 : 0.01f * ap1);
            float e2 = expf(ap2 > 0.f ? ap2 : 0.01f * ap2);
            float e3 = expf(ap3 > 0.f ? ap3 : 0.01f * ap3);
            p.x += e0; p.y += e1; p.z += e2; p.w += e3;
            unsigned slot = i - start;
            if (slot < CAP) {
                *reinterpret_cast<float4*>(&sw[wslot][slot * 4]) =
                    make_float4(sgn * e0, sgn * e1, sgn * e2, sgn * e3);
                ssrc[wslot][slot] = s;
            }
        }
    }
    __syncthreads();

#pragma unroll
    for (int off = 32; off >= 1; off >>= 1) {
        p.x += __shfl_xor(p.x, off);
        p.y += __shfl_xor(p.y, off);
        p.z += __shfl_xor(p.z, off);
        p.w += __shfl_xor(p.w, off);
    }
    if (!valid) return;

    float esq = (q == 0) ? p.x : (q == 1) ? p.y : (q == 2) ? p.z : p.w;
    float rinv = (end > start) ? (1.0f / esq) : 0.f;

    const float* swb = &sw[wslot][0];
    const unsigned* ssb = &ssrc[wslot][0];
    unsigned cend = min(end, start + CAP);
    unsigned cnt_c = cend - start;

    // Phase B: 8-way ILP over LDS-cached {weight, src}
    float a0 = 0.f, a1 = 0.f, a2 = 0.f, a3 = 0.f;
    unsigned t0 = 0;
    for (; t0 + 8 <= cnt_c; t0 += 8) {
        float w0 = swb[(t0 + 0) * 4 + q], w1 = swb[(t0 + 1) * 4 + q];
        float w2 = swb[(t0 + 2) * 4 + q], w3 = swb[(t0 + 3) * 4 + q];
        float w4 = swb[(t0 + 4) * 4 + q], w5 = swb[(t0 + 5) * 4 + q];
        float w6 = swb[(t0 + 6) * 4 + q], w7 = swb[(t0 + 7) * 4 + q];
        unsigned s0 = ssb[t0 + 0], s1 = ssb[t0 + 1];
        unsigned s2 = ssb[t0 + 2], s3 = ssb[t0 + 3];
        unsigned s4 = ssb[t0 + 4], s5 = ssb[t0 + 5];
        unsigned s6 = ssb[t0 + 6], s7 = ssb[t0 + 7];
        float h0 = __half2float(hp[((size_t)s0 << 6) | (unsigned)lane]);
        float h1 = __half2float(hp[((size_t)s1 << 6) | (unsigned)lane]);
        float h2 = __half2float(hp[((size_t)s2 << 6) | (unsigned)lane]);
        float h3 = __half2float(hp[((size_t)s3 << 6) | (unsigned)lane]);
        float h4 = __half2float(hp[((size_t)s4 << 6) | (unsigned)lane]);
        float h5 = __half2float(hp[((size_t)s5 << 6) | (unsigned)lane]);
        float h6 = __half2float(hp[((size_t)s6 << 6) | (unsigned)lane]);
        float h7 = __half2float(hp[((size_t)s7 << 6) | (unsigned)lane]);
        a0 = fmaf(w0, h0, a0); a1 = fmaf(w1, h1, a1);
        a2 = fmaf(w2, h2, a2); a3 = fmaf(w3, h3, a3);
        a0 = fmaf(w4, h4, a0); a1 = fmaf(w5, h5, a1);
        a2 = fmaf(w6, h6, a2); a3 = fmaf(w7, h7, a3);
    }
    for (; t0 < cnt_c; t0++) {
        float w = swb[t0 * 4 + q];
        unsigned s = ssb[t0];
        a0 = fmaf(w, __half2float(hp[((size_t)s << 6) | (unsigned)lane]), a0);
    }
    // fallback: degree > CAP (never for Poisson(20); correct always)
    for (unsigned i = start + cnt_c; i < end; i++) {
        unsigned sp = src_packed[i];
        unsigned s = sp & 0x3FFFFFFFu;
        unsigned c = sp >> 30;
        float g = (c == 0u) ? 1.f : (c == 1u ? -1.f : 0.f);
        float asv = a_src[s * HEADS + q];
        float ap = fmaf(g, asv, adq) + ba;
        float ev = expf(ap > 0.f ? ap : 0.01f * ap);
        a0 = fmaf(ev * g, __half2float(hp[((size_t)s << 6) | (unsigned)lane]), a0);
    }
    out[((size_t)d << 6) | (unsigned)lane] = ((a0 + a1) + (a2 + a3)) * rinv;
}

// ---------------------------------------------------------------------------
extern "C" void kernel_launch(void* const* d_in, const int* in_sizes, int n_in,
                              void* d_out, int out_size, void* d_ws, size_t ws_size,
                              hipStream_t stream)
{
    const float* h       = (const float*)d_in[0];
    const int*   src_idx = (const int*)d_in[1];
    const int*   dst_idx = (const int*)d_in[2];
    const float* W_w     = (const float*)d_in[3];
    const float* b_w     = (const float*)d_in[4];
    const float* W_a     = (const float*)d_in[5];
    const float* b_a     = (const float*)d_in[6];
    const float* W_d     = (const float*)d_in[7];
    const float* b_d     = (const float*)d_in[8];
    const float* W_f     = (const float*)d_in[9];
    const float* b_f     = (const float*)d_in[10];

    int N = in_sizes[0] / F;
    int E = in_sizes[1];
    int nb = (N + 255) / 256;

    char* ws = (char*)d_ws;
    float*    tfeat = (float*)ws;      ws += (size_t)N * F * 4;        // 12.8MB
    __half*   hp    = (__half*)ws;     ws += (size_t)N * F * 2;        // 6.4MB
    double*   u_arr = (double*)ws;     ws += (size_t)N * 8;            // 0.4MB
    double*   v_arr = (double*)ws;     ws += (size_t)N * 8;            // 0.4MB
    float*    a_src = (float*)ws;      ws += (size_t)N * HEADS * 4;    // 0.8MB
    float*    a_dst = (float*)ws;      ws += (size_t)N * HEADS * 4;    // 0.8MB
    unsigned* cnt   = (unsigned*)ws;   ws += (size_t)N * 4;            // 0.2MB
    unsigned* rowptr= (unsigned*)ws;   ws += ((size_t)N + 4) * 4;      // 0.2MB
    unsigned* bsum  = (unsigned*)ws;   ws += 1024;                     // 1KB
    unsigned* pc    = (unsigned*)ws;   ws += (size_t)E * 4;            // 4MB
    unsigned* src_p = (unsigned*)ws;   ws += (size_t)E * 4;            // 4MB

    float* out = (float*)d_out;

    node_kernel<<<2 * nb, 256, 0, stream>>>(
        h, W_w, b_w, W_a, W_d, b_d, W_f, tfeat, hp, u_arr, v_arr, a_src, a_dst,
        cnt, N, nb);

    count_sign_kernel<<<(E + 511) / 512, 256, 0, stream>>>(
        src_idx, dst_idx, u_arr, v_arr, tfeat, W_f, b_f, cnt, pc, E);

    scan1_kernel<<<nb, 256, 0, stream>>>(cnt, rowptr, bsum, N);
    scan3_kernel<<<nb, 256, 0, stream>>>(rowptr, bsum, N, E, nb);

    place_kernel<<<(E + 255) / 256, 256, 0, stream>>>(
        src_idx, dst_idx, pc, rowptr, src_p, E);

    dst_gather_kernel<<<(N * 64 + 255) / 256, 256, 0, stream>>>(
        rowptr, src_p, a_src, a_dst, b_a, hp, out, N);
}